// Round 1
// baseline (902.105 us; speedup 1.0000x reference)
//
#include <hip/hip_runtime.h>
#include <hip/hip_bf16.h>

#define NN 100000
#define NE 1600000
#define GD 128
#define H1 64
#define H2 64
#define NREL 8
#define NBASES 30
#define NBTOT 576   // 8*64 (relations) + 64 (root)

// ---------- prep: Wcat[128][576] = [W_r | root], B2[128][64] = [w_rel ; w_root] ----------
__global__ void prep_kernel(const float* __restrict__ basis,   // [30][128][64]
                            const float* __restrict__ comp,    // [8][30]
                            const float* __restrict__ root,    // [128][64]
                            const float* __restrict__ w_rel,   // [64][64]
                            const float* __restrict__ w_root,  // [64][64]
                            float* __restrict__ Wcat,          // [128][576]
                            float* __restrict__ B2)            // [128][64]
{
    int idx = blockIdx.x * blockDim.x + threadIdx.x;
    const int totalW = GD * NBTOT;          // 73728
    if (idx < totalW) {
        int i = idx / NBTOT;
        int c = idx % NBTOT;
        float v;
        if (c < NREL * H1) {
            int r = c >> 6, o = c & 63;
            float acc = 0.f;
            #pragma unroll 5
            for (int b = 0; b < NBASES; ++b)
                acc += comp[r * NBASES + b] * basis[(b * GD + i) * H1 + o];
            v = acc;
        } else {
            v = root[i * H1 + (c - NREL * H1)];
        }
        Wcat[idx] = v;
    } else {
        int j = idx - totalW;               // 0..8191
        if (j < GD * H2) {
            int i = j / H2, o = j % H2;
            B2[j] = (i < H1) ? w_rel[i * H2 + o] : w_root[(i - H1) * H2 + o];
        }
    }
}

// ---------- count edges per (dst, rel) ----------
__global__ void count_kernel(const int* __restrict__ ei, const int* __restrict__ et,
                             unsigned* __restrict__ cnt)
{
    int e = blockIdx.x * blockDim.x + threadIdx.x;
    if (e >= NE) return;
    int dst = ei[NE + e];
    int r   = et[e];
    atomicAdd(&cnt[dst * NREL + r], 1u);
}

// ---------- single-block exclusive scan of per-node total degree ----------
__global__ void scan_kernel(const unsigned* __restrict__ cnt,
                            unsigned* __restrict__ off,     // [NN+1]
                            unsigned* __restrict__ cursor)  // [NN]
{
    __shared__ unsigned part[1024];
    int t = threadIdx.x;
    const int C = (NN + 1023) / 1024;   // 98
    int lo = t * C, hi = lo + C; if (hi > NN) hi = NN; if (lo > NN) lo = NN;
    unsigned s = 0;
    for (int n = lo; n < hi; ++n) {
        unsigned d = 0;
        #pragma unroll
        for (int r = 0; r < NREL; ++r) d += cnt[n * NREL + r];
        s += d;
    }
    part[t] = s;
    __syncthreads();
    unsigned own = s;
    for (int st = 1; st < 1024; st <<= 1) {
        unsigned v = (t >= st) ? part[t - st] : 0u;
        __syncthreads();
        part[t] += v;
        __syncthreads();
    }
    unsigned run = part[t] - own;       // exclusive prefix
    for (int n = lo; n < hi; ++n) {
        unsigned d = 0;
        #pragma unroll
        for (int r = 0; r < NREL; ++r) d += cnt[n * NREL + r];
        off[n] = run;
        cursor[n] = run;
        run += d;
    }
    if (t == 1023) off[NN] = part[1023];
}

// ---------- scatter edges into CSR (by dst), bake 1/cnt into record ----------
__global__ void scatter_kernel(const int* __restrict__ ei, const int* __restrict__ et,
                               const float* __restrict__ enorm,
                               const unsigned* __restrict__ cnt,
                               unsigned* __restrict__ cursor,
                               unsigned* __restrict__ csr_st, float* __restrict__ csr_w,
                               float* __restrict__ csr_norm)
{
    int e = blockIdx.x * blockDim.x + threadIdx.x;
    if (e >= NE) return;
    int src = ei[e], dst = ei[NE + e], r = et[e];
    unsigned p = atomicAdd(&cursor[dst], 1u);
    csr_st[p] = ((unsigned)src << 3) | (unsigned)r;   // src*8 + r  == y row index
    unsigned c = cnt[dst * NREL + r];
    csr_w[p] = 1.0f / (float)(c > 0u ? c : 1u);
    csr_norm[p] = enorm[e];
}

// ---------- tiled fp32 GEMM: C[M x NB] = A[M x 128] * B[128 x NB] ----------
// MODE 0: cols 0..511 -> y (bf16, [N][8][64]); cols 512..575 -> buf[n*128+64+o] + bias1[o]
// MODE 1: out[n*64+col] = acc + b_rel[col]
template<int MODE>
__global__ __launch_bounds__(256)
void gemm_kernel(const float* __restrict__ A, int lda,
                 const float* __restrict__ B, int ldb,
                 int M,
                 const float* __restrict__ bias,
                 __hip_bfloat16* __restrict__ y,
                 float* __restrict__ buf,
                 float* __restrict__ out)
{
    __shared__ float Alds[64][68];
    __shared__ float Blds[64][68];
    int tid = threadIdx.x;
    int m0 = blockIdx.x * 64;
    int n0 = blockIdx.y * 64;
    int tx = tid & 15, ty = tid >> 4;
    float acc[4][4] = {};
    for (int k0 = 0; k0 < GD; k0 += 64) {
        #pragma unroll
        for (int p = 0; p < 4; ++p) {
            int f4 = p * 256 + tid;
            int rr = f4 >> 4, cc = f4 & 15;   // rr: 0..63, cc: 0..15 (float4 col)
            float4 av = make_float4(0.f, 0.f, 0.f, 0.f);
            if (m0 + rr < M)
                av = *reinterpret_cast<const float4*>(&A[(size_t)(m0 + rr) * lda + k0 + cc * 4]);
            *reinterpret_cast<float4*>(&Alds[rr][cc * 4]) = av;
            float4 bv = *reinterpret_cast<const float4*>(&B[(size_t)(k0 + rr) * ldb + n0 + cc * 4]);
            *reinterpret_cast<float4*>(&Blds[rr][cc * 4]) = bv;
        }
        __syncthreads();
        #pragma unroll 8
        for (int k = 0; k < 64; ++k) {
            float a[4], b[4];
            float4 bv = *reinterpret_cast<const float4*>(&Blds[k][tx * 4]);
            b[0] = bv.x; b[1] = bv.y; b[2] = bv.z; b[3] = bv.w;
            #pragma unroll
            for (int i = 0; i < 4; ++i) a[i] = Alds[ty * 4 + i][k];
            #pragma unroll
            for (int i = 0; i < 4; ++i)
                #pragma unroll
                for (int j = 0; j < 4; ++j)
                    acc[i][j] += a[i] * b[j];
        }
        __syncthreads();
    }
    #pragma unroll
    for (int i = 0; i < 4; ++i) {
        int row = m0 + ty * 4 + i;
        if (row >= M) continue;
        #pragma unroll
        for (int j = 0; j < 4; ++j) {
            int col = n0 + tx * 4 + j;
            float v = acc[i][j];
            if (MODE == 0) {
                if (col < NREL * H1)
                    y[(size_t)row * 512 + col] = __float2bfloat16(v);
                else
                    buf[(size_t)row * 128 + 64 + (col - NREL * H1)] = v + bias[col - NREL * H1];
            } else {
                out[(size_t)row * H2 + col] = v + bias[col];
            }
        }
    }
}

// ---------- RGCN aggregate: wave per node, lane = h1 dim ----------
__global__ void rgcn_aggregate(const unsigned* __restrict__ off,
                               const unsigned* __restrict__ csr_st,
                               const float* __restrict__ csr_w,
                               const __hip_bfloat16* __restrict__ y,
                               float* __restrict__ buf)
{
    int gid = blockIdx.x * blockDim.x + threadIdx.x;
    int n = gid >> 6;
    int lane = gid & 63;
    if (n >= NN) return;
    unsigned s = off[n], e = off[n + 1];
    float acc0 = 0.f, acc1 = 0.f;
    unsigned i = s;
    for (; i + 2 <= e; i += 2) {
        unsigned r0 = csr_st[i], r1 = csr_st[i + 1];
        float w0 = csr_w[i], w1 = csr_w[i + 1];
        acc0 += __bfloat162float(y[(size_t)r0 * 64 + lane]) * w0;
        acc1 += __bfloat162float(y[(size_t)r1 * 64 + lane]) * w1;
    }
    if (i < e)
        acc0 += __bfloat162float(y[(size_t)csr_st[i] * 64 + lane]) * csr_w[i];
    buf[(size_t)n * 128 + 64 + lane] += acc0 + acc1;
}

// ---------- GraphConv aggregate: agg[n] = sum out1[src]*norm ----------
__global__ void graph_aggregate(const unsigned* __restrict__ off,
                                const unsigned* __restrict__ csr_st,
                                const float* __restrict__ csr_norm,
                                float* __restrict__ buf)
{
    int gid = blockIdx.x * blockDim.x + threadIdx.x;
    int n = gid >> 6;
    int lane = gid & 63;
    if (n >= NN) return;
    unsigned s = off[n], e = off[n + 1];
    float acc0 = 0.f, acc1 = 0.f;
    unsigned i = s;
    for (; i + 2 <= e; i += 2) {
        unsigned src0 = csr_st[i] >> 3, src1 = csr_st[i + 1] >> 3;
        float w0 = csr_norm[i], w1 = csr_norm[i + 1];
        acc0 += buf[(size_t)src0 * 128 + 64 + lane] * w0;
        acc1 += buf[(size_t)src1 * 128 + 64 + lane] * w1;
    }
    if (i < e)
        acc0 += buf[(size_t)(csr_st[i] >> 3) * 128 + 64 + lane] * csr_norm[i];
    buf[(size_t)n * 128 + lane] = acc0 + acc1;   // agg region (disjoint from +64 reads)
}

extern "C" void kernel_launch(void* const* d_in, const int* in_sizes, int n_in,
                              void* d_out, int out_size, void* d_ws, size_t ws_size,
                              hipStream_t stream)
{
    const float* node_features = (const float*)d_in[0];
    const int*   edge_index    = (const int*)d_in[1];
    const float* edge_norm     = (const float*)d_in[2];
    const int*   edge_type     = (const int*)d_in[3];
    const float* basis         = (const float*)d_in[4];
    const float* comp          = (const float*)d_in[5];
    const float* root          = (const float*)d_in[6];
    const float* bias1         = (const float*)d_in[7];
    const float* w_rel         = (const float*)d_in[8];
    const float* b_rel         = (const float*)d_in[9];
    const float* w_root        = (const float*)d_in[10];
    float* out = (float*)d_out;

    char* ws = (char*)d_ws;
    size_t o = 0;
    auto alloc = [&](size_t bytes) -> void* {
        o = (o + 511) & ~(size_t)511;
        void* p = ws + o;
        o += bytes;
        return p;
    };
    float*    Wcat     = (float*)alloc((size_t)GD * NBTOT * 4);
    float*    B2       = (float*)alloc((size_t)GD * H2 * 4);
    unsigned* cnt      = (unsigned*)alloc((size_t)NN * NREL * 4);
    unsigned* off_     = (unsigned*)alloc((size_t)(NN + 1) * 4);
    unsigned* cursor   = (unsigned*)alloc((size_t)NN * 4);
    unsigned* csr_st   = (unsigned*)alloc((size_t)NE * 4);
    float*    csr_w    = (float*)alloc((size_t)NE * 4);
    float*    csr_norm = (float*)alloc((size_t)NE * 4);
    __hip_bfloat16* y  = (__hip_bfloat16*)alloc((size_t)NN * 512 * 2);
    float*    buf      = (float*)alloc((size_t)NN * 128 * 4);

    hipMemsetAsync(cnt, 0, (size_t)NN * NREL * 4, stream);

    prep_kernel<<<(GD * NBTOT + GD * H2 + 255) / 256, 256, 0, stream>>>(
        basis, comp, root, w_rel, w_root, Wcat, B2);

    count_kernel<<<(NE + 255) / 256, 256, 0, stream>>>(edge_index, edge_type, cnt);

    scan_kernel<<<1, 1024, 0, stream>>>(cnt, off_, cursor);

    scatter_kernel<<<(NE + 255) / 256, 256, 0, stream>>>(
        edge_index, edge_type, edge_norm, cnt, cursor, csr_st, csr_w, csr_norm);

    dim3 g1((NN + 63) / 64, NBTOT / 64);
    gemm_kernel<0><<<g1, 256, 0, stream>>>(node_features, GD, Wcat, NBTOT, NN,
                                           bias1, y, buf, nullptr);

    rgcn_aggregate<<<(NN * 64 + 255) / 256, 256, 0, stream>>>(off_, csr_st, csr_w, y, buf);

    graph_aggregate<<<(NN * 64 + 255) / 256, 256, 0, stream>>>(off_, csr_st, csr_norm, buf);

    dim3 g2((NN + 63) / 64, 1);
    gemm_kernel<1><<<g2, 256, 0, stream>>>(buf, GD, B2, H2, NN,
                                           b_rel, nullptr, nullptr, out);
}

// Round 2
// 652.470 us; speedup vs baseline: 1.3826x; 1.3826x over previous
//
#include <hip/hip_runtime.h>
#include <hip/hip_bf16.h>

#define NN 100000
#define NE 1600000
#define GD 128
#define H1 64
#define H2 64
#define NREL 8
#define NBASES 30
#define NBTOT 576   // 8*64 (relations) + 64 (root)

#define NODES_PER_BLK 512
#define NBLK ((NN + NODES_PER_BLK - 1) / NODES_PER_BLK)   // 196

// ---------- prep: Wcat[128][576] = [W_r | root], B2[128][64] = [w_rel ; w_root] ----------
__global__ void prep_kernel(const float* __restrict__ basis,   // [30][128][64]
                            const float* __restrict__ comp,    // [8][30]
                            const float* __restrict__ root,    // [128][64]
                            const float* __restrict__ w_rel,   // [64][64]
                            const float* __restrict__ w_root,  // [64][64]
                            float* __restrict__ Wcat,          // [128][576]
                            float* __restrict__ B2)            // [128][64]
{
    int idx = blockIdx.x * blockDim.x + threadIdx.x;
    const int totalW = GD * NBTOT;          // 73728
    if (idx < totalW) {
        int i = idx / NBTOT;
        int c = idx % NBTOT;
        float v;
        if (c < NREL * H1) {
            int r = c >> 6, o = c & 63;
            float acc = 0.f;
            #pragma unroll 5
            for (int b = 0; b < NBASES; ++b)
                acc += comp[r * NBASES + b] * basis[(b * GD + i) * H1 + o];
            v = acc;
        } else {
            v = root[i * H1 + (c - NREL * H1)];
        }
        Wcat[idx] = v;
    } else {
        int j = idx - totalW;               // 0..8191
        if (j < GD * H2) {
            int i = j / H2, o = j % H2;
            B2[j] = (i < H1) ? w_rel[i * H2 + o] : w_root[(i - H1) * H2 + o];
        }
    }
}

// ---------- count edges per (dst, rel) ----------
__global__ void count_kernel(const int* __restrict__ ei, const int* __restrict__ et,
                             unsigned* __restrict__ cnt)
{
    int e = blockIdx.x * blockDim.x + threadIdx.x;
    if (e >= NE) return;
    int dst = ei[NE + e];
    int r   = et[e];
    atomicAdd(&cnt[dst * NREL + r], 1u);
}

// ---------- hierarchical scan, stage 1: per-node degree + per-block sum ----------
__global__ void deg_kernel(const unsigned* __restrict__ cnt,
                           unsigned* __restrict__ deg,
                           unsigned* __restrict__ blkSum)
{
    __shared__ unsigned red[256];
    int b = blockIdx.x, t = threadIdx.x;
    unsigned local = 0;
    #pragma unroll
    for (int q = 0; q < 2; ++q) {
        int n = b * NODES_PER_BLK + q * 256 + t;
        unsigned d = 0;
        if (n < NN) {
            const uint4* p = reinterpret_cast<const uint4*>(&cnt[(size_t)n * 8]);
            uint4 a = p[0], c = p[1];
            d = a.x + a.y + a.z + a.w + c.x + c.y + c.z + c.w;
            deg[n] = d;
        }
        local += d;
    }
    red[t] = local;
    __syncthreads();
    #pragma unroll
    for (int st = 128; st > 0; st >>= 1) {
        if (t < st) red[t] += red[t + st];
        __syncthreads();
    }
    if (t == 0) blkSum[b] = red[0];
}

// ---------- stage 2: scan the 196 block sums (single small block) ----------
__global__ void blkscan_kernel(const unsigned* __restrict__ blkSum,
                               unsigned* __restrict__ blkOff,
                               unsigned* __restrict__ off)
{
    __shared__ unsigned s[256];
    int t = threadIdx.x;
    unsigned v = (t < NBLK) ? blkSum[t] : 0u;
    s[t] = v;
    __syncthreads();
    for (int st = 1; st < 256; st <<= 1) {
        unsigned u = (t >= st) ? s[t - st] : 0u;
        __syncthreads();
        s[t] += u;
        __syncthreads();
    }
    if (t < NBLK) blkOff[t] = s[t] - v;   // exclusive prefix of block sums
    if (t == 255) off[NN] = s[255];       // grand total
}

// ---------- stage 3: intra-block exclusive scan -> off / cursor ----------
__global__ void offsets_kernel(const unsigned* __restrict__ deg,
                               const unsigned* __restrict__ blkOff,
                               unsigned* __restrict__ off,
                               unsigned* __restrict__ cursor)
{
    __shared__ unsigned s[256];
    int b = blockIdx.x, t = threadIdx.x;
    int n0 = b * NODES_PER_BLK + t * 2;
    unsigned d0 = 0, d1 = 0;
    if (n0 + 1 < NN) {
        uint2 dv = *reinterpret_cast<const uint2*>(&deg[n0]);
        d0 = dv.x; d1 = dv.y;
    } else if (n0 < NN) {
        d0 = deg[n0];
    }
    unsigned pair = d0 + d1;
    s[t] = pair;
    __syncthreads();
    for (int st = 1; st < 256; st <<= 1) {
        unsigned u = (t >= st) ? s[t - st] : 0u;
        __syncthreads();
        s[t] += u;
        __syncthreads();
    }
    unsigned ex = s[t] - pair + blkOff[b];
    if (n0 < NN)     { off[n0] = ex;          cursor[n0] = ex; }
    if (n0 + 1 < NN) { off[n0 + 1] = ex + d0; cursor[n0 + 1] = ex + d0; }
}

// ---------- scatter edges into CSR (by dst), bake 1/cnt into record ----------
__global__ void scatter_kernel(const int* __restrict__ ei, const int* __restrict__ et,
                               const float* __restrict__ enorm,
                               const unsigned* __restrict__ cnt,
                               unsigned* __restrict__ cursor,
                               unsigned* __restrict__ csr_st, float* __restrict__ csr_w,
                               float* __restrict__ csr_norm)
{
    int e = blockIdx.x * blockDim.x + threadIdx.x;
    if (e >= NE) return;
    int src = ei[e], dst = ei[NE + e], r = et[e];
    unsigned p = atomicAdd(&cursor[dst], 1u);
    csr_st[p] = ((unsigned)src << 3) | (unsigned)r;   // src*8 + r  == y row index
    unsigned c = cnt[dst * NREL + r];
    csr_w[p] = 1.0f / (float)(c > 0u ? c : 1u);
    csr_norm[p] = enorm[e];
}

// ---------- tiled fp32 GEMM: C[M x NB] = A[M x 128] * B[128 x NB] ----------
// MODE 0: cols 0..511 -> y (bf16, [N][8][64]); cols 512..575 -> buf[n*128+64+o] + bias1[o]
// MODE 1: out[n*64+col] = acc + b_rel[col]
template<int MODE>
__global__ __launch_bounds__(256)
void gemm_kernel(const float* __restrict__ A, int lda,
                 const float* __restrict__ B, int ldb,
                 int M,
                 const float* __restrict__ bias,
                 __hip_bfloat16* __restrict__ y,
                 float* __restrict__ buf,
                 float* __restrict__ out)
{
    __shared__ float Alds[64][68];
    __shared__ float Blds[64][68];
    int tid = threadIdx.x;
    int m0 = blockIdx.x * 64;
    int n0 = blockIdx.y * 64;
    int tx = tid & 15, ty = tid >> 4;
    float acc[4][4] = {};
    for (int k0 = 0; k0 < GD; k0 += 64) {
        #pragma unroll
        for (int p = 0; p < 4; ++p) {
            int f4 = p * 256 + tid;
            int rr = f4 >> 4, cc = f4 & 15;   // rr: 0..63, cc: 0..15 (float4 col)
            float4 av = make_float4(0.f, 0.f, 0.f, 0.f);
            if (m0 + rr < M)
                av = *reinterpret_cast<const float4*>(&A[(size_t)(m0 + rr) * lda + k0 + cc * 4]);
            *reinterpret_cast<float4*>(&Alds[rr][cc * 4]) = av;
            float4 bv = *reinterpret_cast<const float4*>(&B[(size_t)(k0 + rr) * ldb + n0 + cc * 4]);
            *reinterpret_cast<float4*>(&Blds[rr][cc * 4]) = bv;
        }
        __syncthreads();
        #pragma unroll 8
        for (int k = 0; k < 64; ++k) {
            float a[4], b[4];
            float4 bv = *reinterpret_cast<const float4*>(&Blds[k][tx * 4]);
            b[0] = bv.x; b[1] = bv.y; b[2] = bv.z; b[3] = bv.w;
            #pragma unroll
            for (int i = 0; i < 4; ++i) a[i] = Alds[ty * 4 + i][k];
            #pragma unroll
            for (int i = 0; i < 4; ++i)
                #pragma unroll
                for (int j = 0; j < 4; ++j)
                    acc[i][j] += a[i] * b[j];
        }
        __syncthreads();
    }
    #pragma unroll
    for (int i = 0; i < 4; ++i) {
        int row = m0 + ty * 4 + i;
        if (row >= M) continue;
        #pragma unroll
        for (int j = 0; j < 4; ++j) {
            int col = n0 + tx * 4 + j;
            float v = acc[i][j];
            if (MODE == 0) {
                if (col < NREL * H1)
                    y[(size_t)row * 512 + col] = __float2bfloat16(v);
                else
                    buf[(size_t)row * 128 + 64 + (col - NREL * H1)] = v + bias[col - NREL * H1];
            } else {
                out[(size_t)row * H2 + col] = v + bias[col];
            }
        }
    }
}

// ---------- RGCN aggregate: wave per node, lane = h1 dim ----------
__global__ void rgcn_aggregate(const unsigned* __restrict__ off,
                               const unsigned* __restrict__ csr_st,
                               const float* __restrict__ csr_w,
                               const __hip_bfloat16* __restrict__ y,
                               float* __restrict__ buf)
{
    int gid = blockIdx.x * blockDim.x + threadIdx.x;
    int n = gid >> 6;
    int lane = gid & 63;
    if (n >= NN) return;
    unsigned s = off[n], e = off[n + 1];
    float acc0 = 0.f, acc1 = 0.f;
    unsigned i = s;
    for (; i + 2 <= e; i += 2) {
        unsigned r0 = csr_st[i], r1 = csr_st[i + 1];
        float w0 = csr_w[i], w1 = csr_w[i + 1];
        acc0 += __bfloat162float(y[(size_t)r0 * 64 + lane]) * w0;
        acc1 += __bfloat162float(y[(size_t)r1 * 64 + lane]) * w1;
    }
    if (i < e)
        acc0 += __bfloat162float(y[(size_t)csr_st[i] * 64 + lane]) * csr_w[i];
    buf[(size_t)n * 128 + 64 + lane] += acc0 + acc1;
}

// ---------- GraphConv aggregate: agg[n] = sum out1[src]*norm ----------
__global__ void graph_aggregate(const unsigned* __restrict__ off,
                                const unsigned* __restrict__ csr_st,
                                const float* __restrict__ csr_norm,
                                float* __restrict__ buf)
{
    int gid = blockIdx.x * blockDim.x + threadIdx.x;
    int n = gid >> 6;
    int lane = gid & 63;
    if (n >= NN) return;
    unsigned s = off[n], e = off[n + 1];
    float acc0 = 0.f, acc1 = 0.f;
    unsigned i = s;
    for (; i + 2 <= e; i += 2) {
        unsigned src0 = csr_st[i] >> 3, src1 = csr_st[i + 1] >> 3;
        float w0 = csr_norm[i], w1 = csr_norm[i + 1];
        acc0 += buf[(size_t)src0 * 128 + 64 + lane] * w0;
        acc1 += buf[(size_t)src1 * 128 + 64 + lane] * w1;
    }
    if (i < e)
        acc0 += buf[(size_t)(csr_st[i] >> 3) * 128 + 64 + lane] * csr_norm[i];
    buf[(size_t)n * 128 + lane] = acc0 + acc1;   // agg region (disjoint from +64 reads)
}

extern "C" void kernel_launch(void* const* d_in, const int* in_sizes, int n_in,
                              void* d_out, int out_size, void* d_ws, size_t ws_size,
                              hipStream_t stream)
{
    const float* node_features = (const float*)d_in[0];
    const int*   edge_index    = (const int*)d_in[1];
    const float* edge_norm     = (const float*)d_in[2];
    const int*   edge_type     = (const int*)d_in[3];
    const float* basis         = (const float*)d_in[4];
    const float* comp          = (const float*)d_in[5];
    const float* root          = (const float*)d_in[6];
    const float* bias1         = (const float*)d_in[7];
    const float* w_rel         = (const float*)d_in[8];
    const float* b_rel         = (const float*)d_in[9];
    const float* w_root        = (const float*)d_in[10];
    float* out = (float*)d_out;

    char* ws = (char*)d_ws;
    size_t o = 0;
    auto alloc = [&](size_t bytes) -> void* {
        o = (o + 511) & ~(size_t)511;
        void* p = ws + o;
        o += bytes;
        return p;
    };
    float*    Wcat     = (float*)alloc((size_t)GD * NBTOT * 4);
    float*    B2       = (float*)alloc((size_t)GD * H2 * 4);
    unsigned* cnt      = (unsigned*)alloc((size_t)NN * NREL * 4);
    unsigned* off_     = (unsigned*)alloc((size_t)(NN + 1) * 4);
    unsigned* cursor   = (unsigned*)alloc((size_t)NN * 4);
    unsigned* deg      = (unsigned*)alloc((size_t)NN * 4);
    unsigned* blkSum   = (unsigned*)alloc((size_t)NBLK * 4);
    unsigned* blkOff   = (unsigned*)alloc((size_t)NBLK * 4);
    unsigned* csr_st   = (unsigned*)alloc((size_t)NE * 4);
    float*    csr_w    = (float*)alloc((size_t)NE * 4);
    float*    csr_norm = (float*)alloc((size_t)NE * 4);
    __hip_bfloat16* y  = (__hip_bfloat16*)alloc((size_t)NN * 512 * 2);
    float*    buf      = (float*)alloc((size_t)NN * 128 * 4);

    hipMemsetAsync(cnt, 0, (size_t)NN * NREL * 4, stream);

    prep_kernel<<<(GD * NBTOT + GD * H2 + 255) / 256, 256, 0, stream>>>(
        basis, comp, root, w_rel, w_root, Wcat, B2);

    count_kernel<<<(NE + 255) / 256, 256, 0, stream>>>(edge_index, edge_type, cnt);

    deg_kernel<<<NBLK, 256, 0, stream>>>(cnt, deg, blkSum);
    blkscan_kernel<<<1, 256, 0, stream>>>(blkSum, blkOff, off_);
    offsets_kernel<<<NBLK, 256, 0, stream>>>(deg, blkOff, off_, cursor);

    scatter_kernel<<<(NE + 255) / 256, 256, 0, stream>>>(
        edge_index, edge_type, edge_norm, cnt, cursor, csr_st, csr_w, csr_norm);

    dim3 g1((NN + 63) / 64, NBTOT / 64);
    gemm_kernel<0><<<g1, 256, 0, stream>>>(node_features, GD, Wcat, NBTOT, NN,
                                           bias1, y, buf, nullptr);

    rgcn_aggregate<<<(NN * 64 + 255) / 256, 256, 0, stream>>>(off_, csr_st, csr_w, y, buf);

    graph_aggregate<<<(NN * 64 + 255) / 256, 256, 0, stream>>>(off_, csr_st, csr_norm, buf);

    dim3 g2((NN + 63) / 64, 1);
    gemm_kernel<1><<<g2, 256, 0, stream>>>(buf, GD, B2, H2, NN,
                                           b_rel, nullptr, nullptr, out);
}

// Round 3
// 504.556 us; speedup vs baseline: 1.7879x; 1.2932x over previous
//
#include <hip/hip_runtime.h>
#include <hip/hip_bf16.h>

#define NN 100000
#define NE 1600000
#define GD 128
#define H1 64
#define H2 64
#define NREL 8
#define NBASES 30
#define NBTOT 576   // 8*64 (relations) + 64 (root)

#define NODES_PER_BLK 512
#define NBLK ((NN + NODES_PER_BLK - 1) / NODES_PER_BLK)   // 196

typedef __attribute__((ext_vector_type(8))) short bf16x8;
typedef __attribute__((ext_vector_type(4))) float f32x4;

static __device__ __forceinline__ unsigned short f2bf(float x) {
    __hip_bfloat16 h = __float2bfloat16(x);
    return *reinterpret_cast<unsigned short*>(&h);
}

// ---------- prep: WcatT[576][128] bf16 (B^T layout), B2T[64][128] bf16 ----------
__global__ void prep_kernel(const float* __restrict__ basis,   // [30][128][64]
                            const float* __restrict__ comp,    // [8][30]
                            const float* __restrict__ root,    // [128][64]
                            const float* __restrict__ w_rel,   // [64][64]
                            const float* __restrict__ w_root,  // [64][64]
                            unsigned short* __restrict__ WcatT, // [576][128] bf16
                            unsigned short* __restrict__ B2T)   // [64][128] bf16
{
    int idx = blockIdx.x * blockDim.x + threadIdx.x;
    const int totalW = NBTOT * GD;          // 73728
    if (idx < totalW) {
        int c = idx / GD;       // output col 0..575
        int i = idx % GD;       // k 0..127
        float v;
        if (c < NREL * H1) {
            int r = c >> 6, o = c & 63;
            float acc = 0.f;
            #pragma unroll 5
            for (int b = 0; b < NBASES; ++b)
                acc += comp[r * NBASES + b] * basis[(b * GD + i) * H1 + o];
            v = acc;
        } else {
            v = root[i * H1 + (c - NREL * H1)];
        }
        WcatT[idx] = f2bf(v);
    } else {
        int j = idx - totalW;               // 0..8191
        if (j < H2 * GD) {
            int o = j / GD, i = j % GD;
            float v = (i < H1) ? w_rel[i * H2 + o] : w_root[(i - H1) * H2 + o];
            B2T[j] = f2bf(v);
        }
    }
}

// ---------- count edges per (dst, rel) ----------
__global__ void count_kernel(const int* __restrict__ ei, const int* __restrict__ et,
                             unsigned* __restrict__ cnt)
{
    int e = blockIdx.x * blockDim.x + threadIdx.x;
    if (e >= NE) return;
    int dst = ei[NE + e];
    int r   = et[e];
    atomicAdd(&cnt[dst * NREL + r], 1u);
}

// ---------- hierarchical scan, stage 1 ----------
__global__ void deg_kernel(const unsigned* __restrict__ cnt,
                           unsigned* __restrict__ deg,
                           unsigned* __restrict__ blkSum)
{
    __shared__ unsigned red[256];
    int b = blockIdx.x, t = threadIdx.x;
    unsigned local = 0;
    #pragma unroll
    for (int q = 0; q < 2; ++q) {
        int n = b * NODES_PER_BLK + q * 256 + t;
        unsigned d = 0;
        if (n < NN) {
            const uint4* p = reinterpret_cast<const uint4*>(&cnt[(size_t)n * 8]);
            uint4 a = p[0], c = p[1];
            d = a.x + a.y + a.z + a.w + c.x + c.y + c.z + c.w;
            deg[n] = d;
        }
        local += d;
    }
    red[t] = local;
    __syncthreads();
    #pragma unroll
    for (int st = 128; st > 0; st >>= 1) {
        if (t < st) red[t] += red[t + st];
        __syncthreads();
    }
    if (t == 0) blkSum[b] = red[0];
}

// ---------- stage 2 ----------
__global__ void blkscan_kernel(const unsigned* __restrict__ blkSum,
                               unsigned* __restrict__ blkOff,
                               unsigned* __restrict__ off)
{
    __shared__ unsigned s[256];
    int t = threadIdx.x;
    unsigned v = (t < NBLK) ? blkSum[t] : 0u;
    s[t] = v;
    __syncthreads();
    for (int st = 1; st < 256; st <<= 1) {
        unsigned u = (t >= st) ? s[t - st] : 0u;
        __syncthreads();
        s[t] += u;
        __syncthreads();
    }
    if (t < NBLK) blkOff[t] = s[t] - v;
    if (t == 255) off[NN] = s[255];
}

// ---------- stage 3 ----------
__global__ void offsets_kernel(const unsigned* __restrict__ deg,
                               const unsigned* __restrict__ blkOff,
                               unsigned* __restrict__ off,
                               unsigned* __restrict__ cursor)
{
    __shared__ unsigned s[256];
    int b = blockIdx.x, t = threadIdx.x;
    int n0 = b * NODES_PER_BLK + t * 2;
    unsigned d0 = 0, d1 = 0;
    if (n0 + 1 < NN) {
        uint2 dv = *reinterpret_cast<const uint2*>(&deg[n0]);
        d0 = dv.x; d1 = dv.y;
    } else if (n0 < NN) {
        d0 = deg[n0];
    }
    unsigned pair = d0 + d1;
    s[t] = pair;
    __syncthreads();
    for (int st = 1; st < 256; st <<= 1) {
        unsigned u = (t >= st) ? s[t - st] : 0u;
        __syncthreads();
        s[t] += u;
        __syncthreads();
    }
    unsigned ex = s[t] - pair + blkOff[b];
    if (n0 < NN)     { off[n0] = ex;          cursor[n0] = ex; }
    if (n0 + 1 < NN) { off[n0 + 1] = ex + d0; cursor[n0 + 1] = ex + d0; }
}

// ---------- scatter edges into CSR ----------
__global__ void scatter_kernel(const int* __restrict__ ei, const int* __restrict__ et,
                               const float* __restrict__ enorm,
                               const unsigned* __restrict__ cnt,
                               unsigned* __restrict__ cursor,
                               unsigned* __restrict__ csr_st, float* __restrict__ csr_w,
                               float* __restrict__ csr_norm)
{
    int e = blockIdx.x * blockDim.x + threadIdx.x;
    if (e >= NE) return;
    int src = ei[e], dst = ei[NE + e], r = et[e];
    unsigned p = atomicAdd(&cursor[dst], 1u);
    csr_st[p] = ((unsigned)src << 3) | (unsigned)r;
    unsigned c = cnt[dst * NREL + r];
    csr_w[p] = 1.0f / (float)(c > 0u ? c : 1u);
    csr_norm[p] = enorm[e];
}

// ---------- MFMA GEMM: C[M x NT*64] = A[M x 128](fp32->bf16) * Bt[NT*64 x 128]^T ----------
// MODE 0 (NT=9): cols 0..511 -> y bf16 [N][512]; cols 512..575 -> buf[n*128+64+o] + bias
// MODE 1 (NT=1): out[n*64+col] = acc + bias[col]
// XOR-swizzled LDS (T2): 16B slot index ^= (row&7) — conflict-free ds_read_b128.
template<int MODE>
__global__ __launch_bounds__(256)
void mfma_gemm(const float* __restrict__ A,
               const unsigned short* __restrict__ Bt,
               int M,
               const float* __restrict__ bias,
               unsigned short* __restrict__ y,
               float* __restrict__ buf,
               float* __restrict__ out)
{
    constexpr int NT = (MODE == 0) ? 9 : 1;
    __shared__ unsigned short Alds[128 * 128];   // 32 KB, swizzled
    __shared__ unsigned short Blds[64 * 128];    // 16 KB, swizzled

    int tid = threadIdx.x;
    int m0 = blockIdx.x * 128;
    int w = tid >> 6, l = tid & 63;
    int lr = l & 15, lk = l >> 4;       // lane-row / k-chunk (0..3)

    // ---- stage A tile [128][128] fp32 -> bf16 LDS ----
    #pragma unroll
    for (int p = 0; p < 16; ++p) {
        int f = p * 256 + tid;          // 0..4095 float4s
        int r = f >> 5;                 // row 0..127
        int c4 = f & 31;                // float4 col 0..31
        float4 av = make_float4(0.f, 0.f, 0.f, 0.f);
        if (m0 + r < M)
            av = *reinterpret_cast<const float4*>(&A[(size_t)(m0 + r) * GD + c4 * 4]);
        ushort4 bv;
        bv.x = f2bf(av.x); bv.y = f2bf(av.y); bv.z = f2bf(av.z); bv.w = f2bf(av.w);
        int slot = (c4 >> 1) ^ (r & 7);
        int byte = r * 256 + (slot << 4) + ((c4 & 1) << 3);
        *reinterpret_cast<ushort4*>(reinterpret_cast<char*>(Alds) + byte) = bv;
    }

    for (int nt = 0; nt < NT; ++nt) {
        // ---- stage B tile: Bt rows [nt*64, nt*64+64), each 128 bf16 ----
        #pragma unroll
        for (int p = 0; p < 4; ++p) {
            int f = p * 256 + tid;      // 0..1023 16B-chunks
            int c = f >> 4;             // col 0..63
            int slot = f & 15;
            uint4 v = *reinterpret_cast<const uint4*>(&Bt[(size_t)(nt * 64 + c) * GD + slot * 8]);
            int byte = c * 256 + (((slot ^ (c & 7)) << 4));
            *reinterpret_cast<uint4*>(reinterpret_cast<char*>(Blds) + byte) = v;
        }
        __syncthreads();

        // ---- compute: wave w -> rows [w*32, w*32+32), all 64 cols ----
        f32x4 acc[2][4];
        #pragma unroll
        for (int i = 0; i < 2; ++i)
            #pragma unroll
            for (int j = 0; j < 4; ++j)
                acc[i][j] = (f32x4){0.f, 0.f, 0.f, 0.f};

        #pragma unroll
        for (int ks = 0; ks < 4; ++ks) {
            int q = 4 * ks + lk;                    // 16B k-slot index
            int sA = q ^ (lr & 7);
            bf16x8 a0 = *reinterpret_cast<const bf16x8*>(
                reinterpret_cast<char*>(Alds) + (w * 32 + 0 * 16 + lr) * 256 + (sA << 4));
            bf16x8 a1 = *reinterpret_cast<const bf16x8*>(
                reinterpret_cast<char*>(Alds) + (w * 32 + 1 * 16 + lr) * 256 + (sA << 4));
            #pragma unroll
            for (int cf = 0; cf < 4; ++cf) {
                bf16x8 b = *reinterpret_cast<const bf16x8*>(
                    reinterpret_cast<char*>(Blds) + (cf * 16 + lr) * 256 + (sA << 4));
                acc[0][cf] = __builtin_amdgcn_mfma_f32_16x16x32_bf16(a0, b, acc[0][cf], 0, 0, 0);
                acc[1][cf] = __builtin_amdgcn_mfma_f32_16x16x32_bf16(a1, b, acc[1][cf], 0, 0, 0);
            }
        }

        // ---- write this N-tile ----
        #pragma unroll
        for (int rf = 0; rf < 2; ++rf) {
            int rowb = m0 + w * 32 + rf * 16 + lk * 4;
            #pragma unroll
            for (int cf = 0; cf < 4; ++cf) {
                int col = nt * 64 + cf * 16 + lr;
                #pragma unroll
                for (int j = 0; j < 4; ++j) {
                    int row = rowb + j;
                    if (row >= M) continue;
                    float v = acc[rf][cf][j];
                    if (MODE == 0) {
                        if (col < NREL * H1)
                            y[(size_t)row * 512 + col] = f2bf(v);
                        else
                            buf[(size_t)row * 128 + 64 + (col - NREL * H1)] = v + bias[col - NREL * H1];
                    } else {
                        out[(size_t)row * H2 + col] = v + bias[col];
                    }
                }
            }
        }
        __syncthreads();
    }
}

// ---------- RGCN aggregate: wave per node, lane = h1 dim ----------
__global__ void rgcn_aggregate(const unsigned* __restrict__ off,
                               const unsigned* __restrict__ csr_st,
                               const float* __restrict__ csr_w,
                               const unsigned short* __restrict__ y,
                               float* __restrict__ buf)
{
    int gid = blockIdx.x * blockDim.x + threadIdx.x;
    int n = gid >> 6;
    int lane = gid & 63;
    if (n >= NN) return;
    unsigned s = off[n], e = off[n + 1];
    float acc0 = 0.f, acc1 = 0.f;
    unsigned i = s;
    for (; i + 2 <= e; i += 2) {
        unsigned r0 = csr_st[i], r1 = csr_st[i + 1];
        float w0 = csr_w[i], w1 = csr_w[i + 1];
        unsigned u0 = y[(size_t)r0 * 64 + lane], u1 = y[(size_t)r1 * 64 + lane];
        acc0 += __uint_as_float(u0 << 16) * w0;
        acc1 += __uint_as_float(u1 << 16) * w1;
    }
    if (i < e) {
        unsigned u = y[(size_t)csr_st[i] * 64 + lane];
        acc0 += __uint_as_float(u << 16) * csr_w[i];
    }
    buf[(size_t)n * 128 + 64 + lane] += acc0 + acc1;
}

// ---------- GraphConv aggregate ----------
__global__ void graph_aggregate(const unsigned* __restrict__ off,
                                const unsigned* __restrict__ csr_st,
                                const float* __restrict__ csr_norm,
                                float* __restrict__ buf)
{
    int gid = blockIdx.x * blockDim.x + threadIdx.x;
    int n = gid >> 6;
    int lane = gid & 63;
    if (n >= NN) return;
    unsigned s = off[n], e = off[n + 1];
    float acc0 = 0.f, acc1 = 0.f;
    unsigned i = s;
    for (; i + 2 <= e; i += 2) {
        unsigned src0 = csr_st[i] >> 3, src1 = csr_st[i + 1] >> 3;
        float w0 = csr_norm[i], w1 = csr_norm[i + 1];
        acc0 += buf[(size_t)src0 * 128 + 64 + lane] * w0;
        acc1 += buf[(size_t)src1 * 128 + 64 + lane] * w1;
    }
    if (i < e)
        acc0 += buf[(size_t)(csr_st[i] >> 3) * 128 + 64 + lane] * csr_norm[i];
    buf[(size_t)n * 128 + lane] = acc0 + acc1;
}

extern "C" void kernel_launch(void* const* d_in, const int* in_sizes, int n_in,
                              void* d_out, int out_size, void* d_ws, size_t ws_size,
                              hipStream_t stream)
{
    const float* node_features = (const float*)d_in[0];
    const int*   edge_index    = (const int*)d_in[1];
    const float* edge_norm     = (const float*)d_in[2];
    const int*   edge_type     = (const int*)d_in[3];
    const float* basis         = (const float*)d_in[4];
    const float* comp          = (const float*)d_in[5];
    const float* root          = (const float*)d_in[6];
    const float* bias1         = (const float*)d_in[7];
    const float* w_rel         = (const float*)d_in[8];
    const float* b_rel         = (const float*)d_in[9];
    const float* w_root        = (const float*)d_in[10];
    float* out = (float*)d_out;

    char* ws = (char*)d_ws;
    size_t o = 0;
    auto alloc = [&](size_t bytes) -> void* {
        o = (o + 511) & ~(size_t)511;
        void* p = ws + o;
        o += bytes;
        return p;
    };
    unsigned short* WcatT = (unsigned short*)alloc((size_t)NBTOT * GD * 2);
    unsigned short* B2T   = (unsigned short*)alloc((size_t)H2 * GD * 2);
    unsigned* cnt      = (unsigned*)alloc((size_t)NN * NREL * 4);
    unsigned* off_     = (unsigned*)alloc((size_t)(NN + 1) * 4);
    unsigned* cursor   = (unsigned*)alloc((size_t)NN * 4);
    unsigned* deg      = (unsigned*)alloc((size_t)NN * 4);
    unsigned* blkSum   = (unsigned*)alloc((size_t)NBLK * 4);
    unsigned* blkOff   = (unsigned*)alloc((size_t)NBLK * 4);
    unsigned* csr_st   = (unsigned*)alloc((size_t)NE * 4);
    float*    csr_w    = (float*)alloc((size_t)NE * 4);
    float*    csr_norm = (float*)alloc((size_t)NE * 4);
    unsigned short* y  = (unsigned short*)alloc((size_t)NN * 512 * 2);
    float*    buf      = (float*)alloc((size_t)NN * 128 * 4);

    hipMemsetAsync(cnt, 0, (size_t)NN * NREL * 4, stream);

    prep_kernel<<<(NBTOT * GD + H2 * GD + 255) / 256, 256, 0, stream>>>(
        basis, comp, root, w_rel, w_root, WcatT, B2T);

    count_kernel<<<(NE + 255) / 256, 256, 0, stream>>>(edge_index, edge_type, cnt);

    deg_kernel<<<NBLK, 256, 0, stream>>>(cnt, deg, blkSum);
    blkscan_kernel<<<1, 256, 0, stream>>>(blkSum, blkOff, off_);
    offsets_kernel<<<NBLK, 256, 0, stream>>>(deg, blkOff, off_, cursor);

    scatter_kernel<<<(NE + 255) / 256, 256, 0, stream>>>(
        edge_index, edge_type, edge_norm, cnt, cursor, csr_st, csr_w, csr_norm);

    int gblk = (NN + 127) / 128;   // 782
    mfma_gemm<0><<<gblk, 256, 0, stream>>>(node_features, WcatT, NN, bias1, y, buf, nullptr);

    rgcn_aggregate<<<(NN * 64 + 255) / 256, 256, 0, stream>>>(off_, csr_st, csr_w, y, buf);

    graph_aggregate<<<(NN * 64 + 255) / 256, 256, 0, stream>>>(off_, csr_st, csr_norm, buf);

    mfma_gemm<1><<<gblk, 256, 0, stream>>>(buf, B2T, NN, b_rel, nullptr, nullptr, out);
}

// Round 4
// 449.836 us; speedup vs baseline: 2.0054x; 1.1216x over previous
//
#include <hip/hip_runtime.h>
#include <hip/hip_bf16.h>

#define NN 100000
#define NE 1600000
#define GD 128
#define H1 64
#define H2 64
#define NREL 8
#define NBASES 30
#define NBTOT 576   // 8*64 (relations) + 64 (root)

#define NODES_PER_BLK 512
#define NBLK ((NN + NODES_PER_BLK - 1) / NODES_PER_BLK)   // 196

typedef __attribute__((ext_vector_type(8))) short bf16x8;
typedef __attribute__((ext_vector_type(4))) float f32x4;

static __device__ __forceinline__ unsigned short f2bf(float x) {
    __hip_bfloat16 h = __float2bfloat16(x);
    return *reinterpret_cast<unsigned short*>(&h);
}
static __device__ __forceinline__ float bf2f(unsigned short u) {
    return __uint_as_float(((unsigned)u) << 16);
}

// ---------- prep: WcatT[576][128] bf16 (B^T layout), B2T[64][128] bf16 ----------
__global__ void prep_kernel(const float* __restrict__ basis,   // [30][128][64]
                            const float* __restrict__ comp,    // [8][30]
                            const float* __restrict__ root,    // [128][64]
                            const float* __restrict__ w_rel,   // [64][64]
                            const float* __restrict__ w_root,  // [64][64]
                            unsigned short* __restrict__ WcatT, // [576][128] bf16
                            unsigned short* __restrict__ B2T)   // [64][128] bf16
{
    int idx = blockIdx.x * blockDim.x + threadIdx.x;
    const int totalW = NBTOT * GD;          // 73728
    if (idx < totalW) {
        int c = idx / GD;       // output col 0..575
        int i = idx % GD;       // k 0..127
        float v;
        if (c < NREL * H1) {
            int r = c >> 6, o = c & 63;
            float acc = 0.f;
            #pragma unroll 5
            for (int b = 0; b < NBASES; ++b)
                acc += comp[r * NBASES + b] * basis[(b * GD + i) * H1 + o];
            v = acc;
        } else {
            v = root[i * H1 + (c - NREL * H1)];
        }
        WcatT[idx] = f2bf(v);
    } else {
        int j = idx - totalW;               // 0..8191
        if (j < H2 * GD) {
            int o = j / GD, i = j % GD;
            float v = (i < H1) ? w_rel[i * H2 + o] : w_root[(i - H1) * H2 + o];
            B2T[j] = f2bf(v);
        }
    }
}

// ---------- count edges per (dst, rel) ----------
__global__ void count_kernel(const int* __restrict__ ei, const int* __restrict__ et,
                             unsigned* __restrict__ cnt)
{
    int e = blockIdx.x * blockDim.x + threadIdx.x;
    if (e >= NE) return;
    int dst = ei[NE + e];
    int r   = et[e];
    atomicAdd(&cnt[dst * NREL + r], 1u);
}

// ---------- hierarchical scan, stage 1 ----------
__global__ void deg_kernel(const unsigned* __restrict__ cnt,
                           unsigned* __restrict__ deg,
                           unsigned* __restrict__ blkSum)
{
    __shared__ unsigned red[256];
    int b = blockIdx.x, t = threadIdx.x;
    unsigned local = 0;
    #pragma unroll
    for (int q = 0; q < 2; ++q) {
        int n = b * NODES_PER_BLK + q * 256 + t;
        unsigned d = 0;
        if (n < NN) {
            const uint4* p = reinterpret_cast<const uint4*>(&cnt[(size_t)n * 8]);
            uint4 a = p[0], c = p[1];
            d = a.x + a.y + a.z + a.w + c.x + c.y + c.z + c.w;
            deg[n] = d;
        }
        local += d;
    }
    red[t] = local;
    __syncthreads();
    #pragma unroll
    for (int st = 128; st > 0; st >>= 1) {
        if (t < st) red[t] += red[t + st];
        __syncthreads();
    }
    if (t == 0) blkSum[b] = red[0];
}

// ---------- stage 2 ----------
__global__ void blkscan_kernel(const unsigned* __restrict__ blkSum,
                               unsigned* __restrict__ blkOff,
                               unsigned* __restrict__ off)
{
    __shared__ unsigned s[256];
    int t = threadIdx.x;
    unsigned v = (t < NBLK) ? blkSum[t] : 0u;
    s[t] = v;
    __syncthreads();
    for (int st = 1; st < 256; st <<= 1) {
        unsigned u = (t >= st) ? s[t - st] : 0u;
        __syncthreads();
        s[t] += u;
        __syncthreads();
    }
    if (t < NBLK) blkOff[t] = s[t] - v;
    if (t == 255) off[NN] = s[255];
}

// ---------- stage 3 ----------
__global__ void offsets_kernel(const unsigned* __restrict__ deg,
                               const unsigned* __restrict__ blkOff,
                               unsigned* __restrict__ off,
                               unsigned* __restrict__ cursor)
{
    __shared__ unsigned s[256];
    int b = blockIdx.x, t = threadIdx.x;
    int n0 = b * NODES_PER_BLK + t * 2;
    unsigned d0 = 0, d1 = 0;
    if (n0 + 1 < NN) {
        uint2 dv = *reinterpret_cast<const uint2*>(&deg[n0]);
        d0 = dv.x; d1 = dv.y;
    } else if (n0 < NN) {
        d0 = deg[n0];
    }
    unsigned pair = d0 + d1;
    s[t] = pair;
    __syncthreads();
    for (int st = 1; st < 256; st <<= 1) {
        unsigned u = (t >= st) ? s[t - st] : 0u;
        __syncthreads();
        s[t] += u;
        __syncthreads();
    }
    unsigned ex = s[t] - pair + blkOff[b];
    if (n0 < NN)     { off[n0] = ex;          cursor[n0] = ex; }
    if (n0 + 1 < NN) { off[n0 + 1] = ex + d0; cursor[n0 + 1] = ex + d0; }
}

// ---------- scatter edges into CSR: single 8B record {src*8+r, norm} ----------
__global__ void scatter_kernel(const int* __restrict__ ei, const int* __restrict__ et,
                               const float* __restrict__ enorm,
                               unsigned* __restrict__ cursor,
                               uint2* __restrict__ csr)
{
    int e = blockIdx.x * blockDim.x + threadIdx.x;
    if (e >= NE) return;
    int src = ei[e], dst = ei[NE + e], r = et[e];
    unsigned p = atomicAdd(&cursor[dst], 1u);
    csr[p] = make_uint2(((unsigned)src << 3) | (unsigned)r, __float_as_uint(enorm[e]));
}

// ---------- MFMA GEMM ----------
// MODE 0 (NT=9, A fp32): cols 0..511 -> y bf16 [N][512]; cols 512..575 -> root1[n*64+o]+bias
// MODE 1 (NT=1, A bf16 [M][128]): out[n*64+col] = acc + bias[col]
// XOR-swizzled LDS (T2): 16B slot index ^= (row&7) — conflict-free ds_read_b128.
template<int MODE>
__global__ __launch_bounds__(256)
void mfma_gemm(const void* __restrict__ Avoid,
               const unsigned short* __restrict__ Bt,
               int M,
               const float* __restrict__ bias,
               unsigned short* __restrict__ y,
               float* __restrict__ root1,
               float* __restrict__ out)
{
    constexpr int NT = (MODE == 0) ? 9 : 1;
    __shared__ unsigned short Alds[128 * 128];   // 32 KB, swizzled
    __shared__ unsigned short Blds[64 * 128];    // 16 KB, swizzled

    int tid = threadIdx.x;
    int m0 = blockIdx.x * 128;
    int w = tid >> 6, l = tid & 63;
    int lr = l & 15, lk = l >> 4;

    // ---- stage A tile [128][128] -> bf16 LDS ----
    if (MODE == 0) {
        const float* A = (const float*)Avoid;
        #pragma unroll
        for (int p = 0; p < 16; ++p) {
            int f = p * 256 + tid;          // 0..4095 float4s
            int r = f >> 5;                 // row 0..127
            int c4 = f & 31;                // float4 col 0..31
            float4 av = make_float4(0.f, 0.f, 0.f, 0.f);
            if (m0 + r < M)
                av = *reinterpret_cast<const float4*>(&A[(size_t)(m0 + r) * GD + c4 * 4]);
            ushort4 bv;
            bv.x = f2bf(av.x); bv.y = f2bf(av.y); bv.z = f2bf(av.z); bv.w = f2bf(av.w);
            int slot = (c4 >> 1) ^ (r & 7);
            int byte = r * 256 + (slot << 4) + ((c4 & 1) << 3);
            *reinterpret_cast<ushort4*>(reinterpret_cast<char*>(Alds) + byte) = bv;
        }
    } else {
        const unsigned short* A = (const unsigned short*)Avoid;
        #pragma unroll
        for (int p = 0; p < 8; ++p) {
            int f = p * 256 + tid;          // 0..2047 16B-chunks
            int r = f >> 4;                 // row 0..127
            int slot = f & 15;
            uint4 v = make_uint4(0u, 0u, 0u, 0u);
            if (m0 + r < M)
                v = *reinterpret_cast<const uint4*>(&A[(size_t)(m0 + r) * GD + slot * 8]);
            int byte = r * 256 + ((slot ^ (r & 7)) << 4);
            *reinterpret_cast<uint4*>(reinterpret_cast<char*>(Alds) + byte) = v;
        }
    }

    for (int nt = 0; nt < NT; ++nt) {
        #pragma unroll
        for (int p = 0; p < 4; ++p) {
            int f = p * 256 + tid;      // 0..1023 16B-chunks
            int c = f >> 4;             // col 0..63
            int slot = f & 15;
            uint4 v = *reinterpret_cast<const uint4*>(&Bt[(size_t)(nt * 64 + c) * GD + slot * 8]);
            int byte = c * 256 + (((slot ^ (c & 7)) << 4));
            *reinterpret_cast<uint4*>(reinterpret_cast<char*>(Blds) + byte) = v;
        }
        __syncthreads();

        f32x4 acc[2][4];
        #pragma unroll
        for (int i = 0; i < 2; ++i)
            #pragma unroll
            for (int j = 0; j < 4; ++j)
                acc[i][j] = (f32x4){0.f, 0.f, 0.f, 0.f};

        #pragma unroll
        for (int ks = 0; ks < 4; ++ks) {
            int q = 4 * ks + lk;
            int sA = q ^ (lr & 7);
            bf16x8 a0 = *reinterpret_cast<const bf16x8*>(
                reinterpret_cast<char*>(Alds) + (w * 32 + 0 * 16 + lr) * 256 + (sA << 4));
            bf16x8 a1 = *reinterpret_cast<const bf16x8*>(
                reinterpret_cast<char*>(Alds) + (w * 32 + 1 * 16 + lr) * 256 + (sA << 4));
            #pragma unroll
            for (int cf = 0; cf < 4; ++cf) {
                bf16x8 b = *reinterpret_cast<const bf16x8*>(
                    reinterpret_cast<char*>(Blds) + (cf * 16 + lr) * 256 + (sA << 4));
                acc[0][cf] = __builtin_amdgcn_mfma_f32_16x16x32_bf16(a0, b, acc[0][cf], 0, 0, 0);
                acc[1][cf] = __builtin_amdgcn_mfma_f32_16x16x32_bf16(a1, b, acc[1][cf], 0, 0, 0);
            }
        }

        #pragma unroll
        for (int rf = 0; rf < 2; ++rf) {
            int rowb = m0 + w * 32 + rf * 16 + lk * 4;
            #pragma unroll
            for (int cf = 0; cf < 4; ++cf) {
                int col = nt * 64 + cf * 16 + lr;
                #pragma unroll
                for (int j = 0; j < 4; ++j) {
                    int row = rowb + j;
                    if (row >= M) continue;
                    float v = acc[rf][cf][j];
                    if (MODE == 0) {
                        if (col < NREL * H1)
                            y[(size_t)row * 512 + col] = f2bf(v);
                        else
                            root1[(size_t)row * 64 + (col - NREL * H1)] = v + bias[col - NREL * H1];
                    } else {
                        out[(size_t)row * H2 + col] = v + bias[col];
                    }
                }
            }
        }
        __syncthreads();
    }
}

// ---------- RGCN aggregate: wave per node, lane = h1 dim ----------
// out1 = root1[n] + sum_edges y[src*8+r] / cnt[n][r]  -> abuf[n][64+lane] (bf16)
__global__ void rgcn_aggregate(const unsigned* __restrict__ off,
                               const uint2* __restrict__ csr,
                               const unsigned* __restrict__ cnt,
                               const unsigned short* __restrict__ y,
                               const float* __restrict__ root1,
                               unsigned short* __restrict__ abuf)
{
    int gid = blockIdx.x * blockDim.x + threadIdx.x;
    int n = gid >> 6;
    int lane = gid & 63;
    if (n >= NN) return;
    // preload this node's 8 inverse counts into lanes 0..7
    unsigned myc = (lane < NREL) ? cnt[(size_t)n * NREL + lane] : 1u;
    float myinv = 1.0f / (float)(myc > 0u ? myc : 1u);
    unsigned s = off[n], e = off[n + 1];
    float acc0 = 0.f, acc1 = 0.f;
    unsigned i = s;
    for (; i + 2 <= e; i += 2) {
        uint2 r0 = csr[i], r1 = csr[i + 1];
        float w0 = __shfl(myinv, (int)(r0.x & 7));
        float w1 = __shfl(myinv, (int)(r1.x & 7));
        acc0 += bf2f(y[(size_t)r0.x * 64 + lane]) * w0;
        acc1 += bf2f(y[(size_t)r1.x * 64 + lane]) * w1;
    }
    if (i < e) {
        uint2 r0 = csr[i];
        float w0 = __shfl(myinv, (int)(r0.x & 7));
        acc0 += bf2f(y[(size_t)r0.x * 64 + lane]) * w0;
    }
    float out1 = root1[(size_t)n * 64 + lane] + acc0 + acc1;
    abuf[(size_t)n * 128 + 64 + lane] = f2bf(out1);
}

// ---------- GraphConv aggregate: agg[n] = sum out1[src]*norm -> abuf[n][lane] (bf16) ----------
__global__ void graph_aggregate(const unsigned* __restrict__ off,
                                const uint2* __restrict__ csr,
                                unsigned short* __restrict__ abuf)
{
    int gid = blockIdx.x * blockDim.x + threadIdx.x;
    int n = gid >> 6;
    int lane = gid & 63;
    if (n >= NN) return;
    unsigned s = off[n], e = off[n + 1];
    float acc0 = 0.f, acc1 = 0.f;
    unsigned i = s;
    for (; i + 2 <= e; i += 2) {
        uint2 r0 = csr[i], r1 = csr[i + 1];
        unsigned src0 = r0.x >> 3, src1 = r1.x >> 3;
        acc0 += bf2f(abuf[(size_t)src0 * 128 + 64 + lane]) * __uint_as_float(r0.y);
        acc1 += bf2f(abuf[(size_t)src1 * 128 + 64 + lane]) * __uint_as_float(r1.y);
    }
    if (i < e) {
        uint2 r0 = csr[i];
        acc0 += bf2f(abuf[(size_t)(r0.x >> 3) * 128 + 64 + lane]) * __uint_as_float(r0.y);
    }
    abuf[(size_t)n * 128 + lane] = f2bf(acc0 + acc1);   // disjoint from +64 reads
}

extern "C" void kernel_launch(void* const* d_in, const int* in_sizes, int n_in,
                              void* d_out, int out_size, void* d_ws, size_t ws_size,
                              hipStream_t stream)
{
    const float* node_features = (const float*)d_in[0];
    const int*   edge_index    = (const int*)d_in[1];
    const float* edge_norm     = (const float*)d_in[2];
    const int*   edge_type     = (const int*)d_in[3];
    const float* basis         = (const float*)d_in[4];
    const float* comp          = (const float*)d_in[5];
    const float* root          = (const float*)d_in[6];
    const float* bias1         = (const float*)d_in[7];
    const float* w_rel         = (const float*)d_in[8];
    const float* b_rel         = (const float*)d_in[9];
    const float* w_root        = (const float*)d_in[10];
    float* out = (float*)d_out;

    char* ws = (char*)d_ws;
    size_t o = 0;
    auto alloc = [&](size_t bytes) -> void* {
        o = (o + 511) & ~(size_t)511;
        void* p = ws + o;
        o += bytes;
        return p;
    };
    unsigned short* WcatT = (unsigned short*)alloc((size_t)NBTOT * GD * 2);
    unsigned short* B2T   = (unsigned short*)alloc((size_t)H2 * GD * 2);
    unsigned* cnt      = (unsigned*)alloc((size_t)NN * NREL * 4);
    unsigned* off_     = (unsigned*)alloc((size_t)(NN + 1) * 4);
    unsigned* cursor   = (unsigned*)alloc((size_t)NN * 4);
    unsigned* deg      = (unsigned*)alloc((size_t)NN * 4);
    unsigned* blkSum   = (unsigned*)alloc((size_t)NBLK * 4);
    unsigned* blkOff   = (unsigned*)alloc((size_t)NBLK * 4);
    uint2*    csr      = (uint2*)alloc((size_t)NE * 8);
    unsigned short* y  = (unsigned short*)alloc((size_t)NN * 512 * 2);
    float*    root1    = (float*)alloc((size_t)NN * 64 * 4);
    unsigned short* abuf = (unsigned short*)alloc((size_t)NN * 128 * 2);

    hipMemsetAsync(cnt, 0, (size_t)NN * NREL * 4, stream);

    prep_kernel<<<(NBTOT * GD + H2 * GD + 255) / 256, 256, 0, stream>>>(
        basis, comp, root, w_rel, w_root, WcatT, B2T);

    count_kernel<<<(NE + 255) / 256, 256, 0, stream>>>(edge_index, edge_type, cnt);

    deg_kernel<<<NBLK, 256, 0, stream>>>(cnt, deg, blkSum);
    blkscan_kernel<<<1, 256, 0, stream>>>(blkSum, blkOff, off_);
    offsets_kernel<<<NBLK, 256, 0, stream>>>(deg, blkOff, off_, cursor);

    scatter_kernel<<<(NE + 255) / 256, 256, 0, stream>>>(
        edge_index, edge_type, edge_norm, cursor, csr);

    int gblk = (NN + 127) / 128;   // 782
    mfma_gemm<0><<<gblk, 256, 0, stream>>>(node_features, WcatT, NN, bias1, y, root1, nullptr);

    rgcn_aggregate<<<(NN * 64 + 255) / 256, 256, 0, stream>>>(off_, csr, cnt, y, root1, abuf);

    graph_aggregate<<<(NN * 64 + 255) / 256, 256, 0, stream>>>(off_, csr, abuf);

    mfma_gemm<1><<<gblk, 256, 0, stream>>>(abuf, B2T, NN, b_rel, nullptr, nullptr, out);
}

// Round 5
// 403.877 us; speedup vs baseline: 2.2336x; 1.1138x over previous
//
#include <hip/hip_runtime.h>
#include <hip/hip_bf16.h>

#define NN 100000
#define NE 1600000
#define GD 128
#define H1 64
#define H2 64
#define NREL 8
#define NBASES 30
#define NBTOT 576   // 8*64 (relations) + 64 (root)

#define NODES_PER_BLK 512
#define NBLK ((NN + NODES_PER_BLK - 1) / NODES_PER_BLK)   // 196

#define NPB 256                               // nodes per bucket
#define NBUCK ((NN + NPB - 1) / NPB)          // 391
#define NWGA 128
#define ECHUNK ((NE + NWGA - 1) / NWGA)       // 12500

typedef __attribute__((ext_vector_type(8))) short bf16x8;
typedef __attribute__((ext_vector_type(4))) float f32x4;

static __device__ __forceinline__ unsigned short f2bf(float x) {
    __hip_bfloat16 h = __float2bfloat16(x);
    return *reinterpret_cast<unsigned short*>(&h);
}
static __device__ __forceinline__ float bf2f(unsigned short u) {
    return __uint_as_float(((unsigned)u) << 16);
}

// ---------- prep: WcatT[576][128] bf16 (B^T layout), B2T[64][128] bf16 ----------
__global__ void prep_kernel(const float* __restrict__ basis,   // [30][128][64]
                            const float* __restrict__ comp,    // [8][30]
                            const float* __restrict__ root,    // [128][64]
                            const float* __restrict__ w_rel,   // [64][64]
                            const float* __restrict__ w_root,  // [64][64]
                            unsigned short* __restrict__ WcatT, // [576][128] bf16
                            unsigned short* __restrict__ B2T)   // [64][128] bf16
{
    int idx = blockIdx.x * blockDim.x + threadIdx.x;
    const int totalW = NBTOT * GD;          // 73728
    if (idx < totalW) {
        int c = idx / GD;       // output col 0..575
        int i = idx % GD;       // k 0..127
        float v;
        if (c < NREL * H1) {
            int r = c >> 6, o = c & 63;
            float acc = 0.f;
            #pragma unroll 5
            for (int b = 0; b < NBASES; ++b)
                acc += comp[r * NBASES + b] * basis[(b * GD + i) * H1 + o];
            v = acc;
        } else {
            v = root[i * H1 + (c - NREL * H1)];
        }
        WcatT[idx] = f2bf(v);
    } else {
        int j = idx - totalW;               // 0..8191
        if (j < H2 * GD) {
            int o = j / GD, i = j % GD;
            float v = (i < H1) ? w_rel[i * H2 + o] : w_root[(i - H1) * H2 + o];
            B2T[j] = f2bf(v);
        }
    }
}

// ---------- count edges per (dst, rel) ----------
__global__ void count_kernel(const int* __restrict__ ei, const int* __restrict__ et,
                             unsigned* __restrict__ cnt)
{
    int e = blockIdx.x * blockDim.x + threadIdx.x;
    if (e >= NE) return;
    int dst = ei[NE + e];
    int r   = et[e];
    atomicAdd(&cnt[dst * NREL + r], 1u);
}

// ---------- hierarchical scan, stage 1 ----------
__global__ void deg_kernel(const unsigned* __restrict__ cnt,
                           unsigned* __restrict__ deg,
                           unsigned* __restrict__ blkSum)
{
    __shared__ unsigned red[256];
    int b = blockIdx.x, t = threadIdx.x;
    unsigned local = 0;
    #pragma unroll
    for (int q = 0; q < 2; ++q) {
        int n = b * NODES_PER_BLK + q * 256 + t;
        unsigned d = 0;
        if (n < NN) {
            const uint4* p = reinterpret_cast<const uint4*>(&cnt[(size_t)n * 8]);
            uint4 a = p[0], c = p[1];
            d = a.x + a.y + a.z + a.w + c.x + c.y + c.z + c.w;
            deg[n] = d;
        }
        local += d;
    }
    red[t] = local;
    __syncthreads();
    #pragma unroll
    for (int st = 128; st > 0; st >>= 1) {
        if (t < st) red[t] += red[t + st];
        __syncthreads();
    }
    if (t == 0) blkSum[b] = red[0];
}

// ---------- stage 2 ----------
__global__ void blkscan_kernel(const unsigned* __restrict__ blkSum,
                               unsigned* __restrict__ blkOff,
                               unsigned* __restrict__ off)
{
    __shared__ unsigned s[256];
    int t = threadIdx.x;
    unsigned v = (t < NBLK) ? blkSum[t] : 0u;
    s[t] = v;
    __syncthreads();
    for (int st = 1; st < 256; st <<= 1) {
        unsigned u = (t >= st) ? s[t - st] : 0u;
        __syncthreads();
        s[t] += u;
        __syncthreads();
    }
    if (t < NBLK) blkOff[t] = s[t] - v;
    if (t == 255) off[NN] = s[255];
}

// ---------- stage 3: off[] + per-bucket bases ----------
__global__ void offsets_kernel(const unsigned* __restrict__ deg,
                               const unsigned* __restrict__ blkOff,
                               unsigned* __restrict__ off,
                               unsigned* __restrict__ bcur)
{
    __shared__ unsigned s[256];
    int b = blockIdx.x, t = threadIdx.x;
    int n0 = b * NODES_PER_BLK + t * 2;
    unsigned d0 = 0, d1 = 0;
    if (n0 + 1 < NN) {
        uint2 dv = *reinterpret_cast<const uint2*>(&deg[n0]);
        d0 = dv.x; d1 = dv.y;
    } else if (n0 < NN) {
        d0 = deg[n0];
    }
    unsigned pair = d0 + d1;
    s[t] = pair;
    __syncthreads();
    for (int st = 1; st < 256; st <<= 1) {
        unsigned u = (t >= st) ? s[t - st] : 0u;
        __syncthreads();
        s[t] += u;
        __syncthreads();
    }
    unsigned ex = s[t] - pair + blkOff[b];
    if (n0 < NN) {
        off[n0] = ex;
        if ((n0 & (NPB - 1)) == 0) bcur[n0 >> 8] = ex;
    }
    if (n0 + 1 < NN) off[n0 + 1] = ex + d0;
}

// ---------- partition phase A: bucket-grouped records, coalesced writes ----------
// tmp record: {(dstlocal<<24)|(src<<3)|r, norm_bits}
__global__ __launch_bounds__(512)
void partition_a(const int* __restrict__ ei, const int* __restrict__ et,
                 const float* __restrict__ enorm,
                 unsigned* __restrict__ bcur,
                 uint2* __restrict__ tmp)
{
    __shared__ unsigned lcnt[NBUCK], wbase[NBUCK], lcur[NBUCK];
    int t = threadIdx.x;
    int c0 = blockIdx.x * ECHUNK;
    int c1 = c0 + ECHUNK; if (c1 > NE) c1 = NE;
    for (int i = t; i < NBUCK; i += 512) { lcnt[i] = 0; lcur[i] = 0; }
    __syncthreads();
    for (int e = c0 + t; e < c1; e += 512) {
        int dst = ei[NE + e];
        atomicAdd(&lcnt[dst >> 8], 1u);
    }
    __syncthreads();
    for (int i = t; i < NBUCK; i += 512)
        wbase[i] = atomicAdd(&bcur[i], lcnt[i]);
    __syncthreads();
    for (int e = c0 + t; e < c1; e += 512) {
        int src = ei[e], dst = ei[NE + e], r = et[e];
        int b = dst >> 8;
        unsigned pos = wbase[b] + atomicAdd(&lcur[b], 1u);
        unsigned dl = (unsigned)(dst & (NPB - 1));
        tmp[pos] = make_uint2((dl << 24) | ((unsigned)src << 3) | (unsigned)r,
                              __float_as_uint(enorm[e]));
    }
}

// ---------- partition phase B: per-bucket scatter into final CSR ----------
__global__ __launch_bounds__(256)
void partition_b(const unsigned* __restrict__ off,
                 const uint2* __restrict__ tmp,
                 uint2* __restrict__ csr)
{
    __shared__ unsigned lcur[NPB];
    int b = blockIdx.x, t = threadIdx.x;
    int nlo = b * NPB;
    int nn = NN - nlo; if (nn > NPB) nn = NPB;
    if (t < nn) lcur[t] = off[nlo + t];
    __syncthreads();
    unsigned bstart = off[nlo];
    unsigned bend = off[nlo + nn];
    for (unsigned j = bstart + t; j < bend; j += 256) {
        uint2 rec = tmp[j];
        unsigned dl = rec.x >> 24;
        unsigned p = atomicAdd(&lcur[dl], 1u);
        csr[p] = make_uint2(rec.x & 0x00FFFFFFu, rec.y);
    }
}

// ---------- MFMA GEMM ----------
// MODE 0 (NT=9, A fp32): cols 0..511 -> y bf16 [N][512]; cols 512..575 -> root1[n*64+o]+bias
// MODE 1 (NT=1, A bf16 [M][128]): out[n*64+col] = acc + bias[col]
// XOR-swizzled LDS (T2): 16B slot index ^= (row&7) — conflict-free ds_read_b128.
template<int MODE>
__global__ __launch_bounds__(256)
void mfma_gemm(const void* __restrict__ Avoid,
               const unsigned short* __restrict__ Bt,
               int M,
               const float* __restrict__ bias,
               unsigned short* __restrict__ y,
               float* __restrict__ root1,
               float* __restrict__ out)
{
    constexpr int NT = (MODE == 0) ? 9 : 1;
    __shared__ unsigned short Alds[128 * 128];   // 32 KB, swizzled
    __shared__ unsigned short Blds[64 * 128];    // 16 KB, swizzled

    int tid = threadIdx.x;
    int m0 = blockIdx.x * 128;
    int w = tid >> 6, l = tid & 63;
    int lr = l & 15, lk = l >> 4;

    if (MODE == 0) {
        const float* A = (const float*)Avoid;
        #pragma unroll
        for (int p = 0; p < 16; ++p) {
            int f = p * 256 + tid;          // 0..4095 float4s
            int r = f >> 5;                 // row 0..127
            int c4 = f & 31;                // float4 col 0..31
            float4 av = make_float4(0.f, 0.f, 0.f, 0.f);
            if (m0 + r < M)
                av = *reinterpret_cast<const float4*>(&A[(size_t)(m0 + r) * GD + c4 * 4]);
            ushort4 bv;
            bv.x = f2bf(av.x); bv.y = f2bf(av.y); bv.z = f2bf(av.z); bv.w = f2bf(av.w);
            int slot = (c4 >> 1) ^ (r & 7);
            int byte = r * 256 + (slot << 4) + ((c4 & 1) << 3);
            *reinterpret_cast<ushort4*>(reinterpret_cast<char*>(Alds) + byte) = bv;
        }
    } else {
        const unsigned short* A = (const unsigned short*)Avoid;
        #pragma unroll
        for (int p = 0; p < 8; ++p) {
            int f = p * 256 + tid;          // 0..2047 16B-chunks
            int r = f >> 4;                 // row 0..127
            int slot = f & 15;
            uint4 v = make_uint4(0u, 0u, 0u, 0u);
            if (m0 + r < M)
                v = *reinterpret_cast<const uint4*>(&A[(size_t)(m0 + r) * GD + slot * 8]);
            int byte = r * 256 + ((slot ^ (r & 7)) << 4);
            *reinterpret_cast<uint4*>(reinterpret_cast<char*>(Alds) + byte) = v;
        }
    }

    for (int nt = 0; nt < NT; ++nt) {
        #pragma unroll
        for (int p = 0; p < 4; ++p) {
            int f = p * 256 + tid;      // 0..1023 16B-chunks
            int c = f >> 4;             // col 0..63
            int slot = f & 15;
            uint4 v = *reinterpret_cast<const uint4*>(&Bt[(size_t)(nt * 64 + c) * GD + slot * 8]);
            int byte = c * 256 + (((slot ^ (c & 7)) << 4));
            *reinterpret_cast<uint4*>(reinterpret_cast<char*>(Blds) + byte) = v;
        }
        __syncthreads();

        f32x4 acc[2][4];
        #pragma unroll
        for (int i = 0; i < 2; ++i)
            #pragma unroll
            for (int j = 0; j < 4; ++j)
                acc[i][j] = (f32x4){0.f, 0.f, 0.f, 0.f};

        #pragma unroll
        for (int ks = 0; ks < 4; ++ks) {
            int q = 4 * ks + lk;
            int sA = q ^ (lr & 7);
            bf16x8 a0 = *reinterpret_cast<const bf16x8*>(
                reinterpret_cast<char*>(Alds) + (w * 32 + 0 * 16 + lr) * 256 + (sA << 4));
            bf16x8 a1 = *reinterpret_cast<const bf16x8*>(
                reinterpret_cast<char*>(Alds) + (w * 32 + 1 * 16 + lr) * 256 + (sA << 4));
            #pragma unroll
            for (int cf = 0; cf < 4; ++cf) {
                bf16x8 b = *reinterpret_cast<const bf16x8*>(
                    reinterpret_cast<char*>(Blds) + (cf * 16 + lr) * 256 + (sA << 4));
                acc[0][cf] = __builtin_amdgcn_mfma_f32_16x16x32_bf16(a0, b, acc[0][cf], 0, 0, 0);
                acc[1][cf] = __builtin_amdgcn_mfma_f32_16x16x32_bf16(a1, b, acc[1][cf], 0, 0, 0);
            }
        }

        #pragma unroll
        for (int rf = 0; rf < 2; ++rf) {
            int rowb = m0 + w * 32 + rf * 16 + lk * 4;
            #pragma unroll
            for (int cf = 0; cf < 4; ++cf) {
                int col = nt * 64 + cf * 16 + lr;
                #pragma unroll
                for (int j = 0; j < 4; ++j) {
                    int row = rowb + j;
                    if (row >= M) continue;
                    float v = acc[rf][cf][j];
                    if (MODE == 0) {
                        if (col < NREL * H1)
                            y[(size_t)row * 512 + col] = f2bf(v);
                        else
                            root1[(size_t)row * 64 + (col - NREL * H1)] = v + bias[col - NREL * H1];
                    } else {
                        out[(size_t)row * H2 + col] = v + bias[col];
                    }
                }
            }
        }
        __syncthreads();
    }
}

// ---------- RGCN aggregate: wave per node, lane = h1 dim ----------
__global__ void rgcn_aggregate(const unsigned* __restrict__ off,
                               const uint2* __restrict__ csr,
                               const unsigned* __restrict__ cnt,
                               const unsigned short* __restrict__ y,
                               const float* __restrict__ root1,
                               unsigned short* __restrict__ abuf)
{
    int gid = blockIdx.x * blockDim.x + threadIdx.x;
    int n = gid >> 6;
    int lane = gid & 63;
    if (n >= NN) return;
    unsigned myc = (lane < NREL) ? cnt[(size_t)n * NREL + lane] : 1u;
    float myinv = 1.0f / (float)(myc > 0u ? myc : 1u);
    unsigned s = off[n], e = off[n + 1];
    float acc0 = 0.f, acc1 = 0.f;
    unsigned i = s;
    for (; i + 2 <= e; i += 2) {
        uint2 r0 = csr[i], r1 = csr[i + 1];
        float w0 = __shfl(myinv, (int)(r0.x & 7));
        float w1 = __shfl(myinv, (int)(r1.x & 7));
        acc0 += bf2f(y[(size_t)r0.x * 64 + lane]) * w0;
        acc1 += bf2f(y[(size_t)r1.x * 64 + lane]) * w1;
    }
    if (i < e) {
        uint2 r0 = csr[i];
        float w0 = __shfl(myinv, (int)(r0.x & 7));
        acc0 += bf2f(y[(size_t)r0.x * 64 + lane]) * w0;
    }
    float out1 = root1[(size_t)n * 64 + lane] + acc0 + acc1;
    abuf[(size_t)n * 128 + 64 + lane] = f2bf(out1);
}

// ---------- GraphConv aggregate ----------
__global__ void graph_aggregate(const unsigned* __restrict__ off,
                                const uint2* __restrict__ csr,
                                unsigned short* __restrict__ abuf)
{
    int gid = blockIdx.x * blockDim.x + threadIdx.x;
    int n = gid >> 6;
    int lane = gid & 63;
    if (n >= NN) return;
    unsigned s = off[n], e = off[n + 1];
    float acc0 = 0.f, acc1 = 0.f;
    unsigned i = s;
    for (; i + 2 <= e; i += 2) {
        uint2 r0 = csr[i], r1 = csr[i + 1];
        unsigned src0 = r0.x >> 3, src1 = r1.x >> 3;
        acc0 += bf2f(abuf[(size_t)src0 * 128 + 64 + lane]) * __uint_as_float(r0.y);
        acc1 += bf2f(abuf[(size_t)src1 * 128 + 64 + lane]) * __uint_as_float(r1.y);
    }
    if (i < e) {
        uint2 r0 = csr[i];
        acc0 += bf2f(abuf[(size_t)(r0.x >> 3) * 128 + 64 + lane]) * __uint_as_float(r0.y);
    }
    abuf[(size_t)n * 128 + lane] = f2bf(acc0 + acc1);
}

extern "C" void kernel_launch(void* const* d_in, const int* in_sizes, int n_in,
                              void* d_out, int out_size, void* d_ws, size_t ws_size,
                              hipStream_t stream)
{
    const float* node_features = (const float*)d_in[0];
    const int*   edge_index    = (const int*)d_in[1];
    const float* edge_norm     = (const float*)d_in[2];
    const int*   edge_type     = (const int*)d_in[3];
    const float* basis         = (const float*)d_in[4];
    const float* comp          = (const float*)d_in[5];
    const float* root          = (const float*)d_in[6];
    const float* bias1         = (const float*)d_in[7];
    const float* w_rel         = (const float*)d_in[8];
    const float* b_rel         = (const float*)d_in[9];
    const float* w_root        = (const float*)d_in[10];
    float* out = (float*)d_out;

    char* ws = (char*)d_ws;
    size_t o = 0;
    auto alloc = [&](size_t bytes) -> void* {
        o = (o + 511) & ~(size_t)511;
        void* p = ws + o;
        o += bytes;
        return p;
    };
    unsigned short* WcatT = (unsigned short*)alloc((size_t)NBTOT * GD * 2);
    unsigned short* B2T   = (unsigned short*)alloc((size_t)H2 * GD * 2);
    unsigned* cnt      = (unsigned*)alloc((size_t)NN * NREL * 4);
    unsigned* off_     = (unsigned*)alloc((size_t)(NN + 1) * 4);
    unsigned* bcur     = (unsigned*)alloc((size_t)NBUCK * 4);
    unsigned* deg      = (unsigned*)alloc((size_t)NN * 4);
    unsigned* blkSum   = (unsigned*)alloc((size_t)NBLK * 4);
    unsigned* blkOff   = (unsigned*)alloc((size_t)NBLK * 4);
    uint2*    csr      = (uint2*)alloc((size_t)NE * 8);
    unsigned short* y  = (unsigned short*)alloc((size_t)NN * 512 * 2);
    float*    root1    = (float*)alloc((size_t)NN * 64 * 4);
    unsigned short* abuf = (unsigned short*)alloc((size_t)NN * 128 * 2);
    uint2*    tmp      = (uint2*)abuf;   // alias: tmp dead before abuf's first write
    // (abuf is 25.6 MB >= tmp's 12.8 MB; tmp used partition_a->partition_b only)

    hipMemsetAsync(cnt, 0, (size_t)NN * NREL * 4, stream);

    prep_kernel<<<(NBTOT * GD + H2 * GD + 255) / 256, 256, 0, stream>>>(
        basis, comp, root, w_rel, w_root, WcatT, B2T);

    count_kernel<<<(NE + 255) / 256, 256, 0, stream>>>(edge_index, edge_type, cnt);

    deg_kernel<<<NBLK, 256, 0, stream>>>(cnt, deg, blkSum);
    blkscan_kernel<<<1, 256, 0, stream>>>(blkSum, blkOff, off_);
    offsets_kernel<<<NBLK, 256, 0, stream>>>(deg, blkOff, off_, bcur);

    partition_a<<<NWGA, 512, 0, stream>>>(edge_index, edge_type, edge_norm, bcur, tmp);
    partition_b<<<NBUCK, 256, 0, stream>>>(off_, tmp, csr);

    int gblk = (NN + 127) / 128;   // 782
    mfma_gemm<0><<<gblk, 256, 0, stream>>>(node_features, WcatT, NN, bias1, y, root1, nullptr);

    rgcn_aggregate<<<(NN * 64 + 255) / 256, 256, 0, stream>>>(off_, csr, cnt, y, root1, abuf);

    graph_aggregate<<<(NN * 64 + 255) / 256, 256, 0, stream>>>(off_, csr, abuf);

    mfma_gemm<1><<<gblk, 256, 0, stream>>>(abuf, B2T, NN, b_rel, nullptr, nullptr, out);
}

// Round 6
// 300.369 us; speedup vs baseline: 3.0033x; 1.3446x over previous
//
#include <hip/hip_runtime.h>
#include <hip/hip_bf16.h>

#define NN 100000
#define NE 1600000
#define GD 128
#define H1 64
#define H2 64
#define NREL 8
#define NBASES 30
#define NBTOT 576   // 8*64 (relations) + 64 (root)

#define NPB 256                               // nodes per bucket
#define NBUCK ((NN + NPB - 1) / NPB)          // 391
#define NWGA 128
#define ECHUNK ((NE + NWGA - 1) / NWGA)       // 12500

typedef __attribute__((ext_vector_type(8))) short bf16x8;
typedef __attribute__((ext_vector_type(4))) float f32x4;

static __device__ __forceinline__ unsigned short f2bf(float x) {
    __hip_bfloat16 h = __float2bfloat16(x);
    return *reinterpret_cast<unsigned short*>(&h);
}
static __device__ __forceinline__ float bf2f(unsigned short u) {
    return __uint_as_float(((unsigned)u) << 16);
}

// ---------- prep: WcatT[576][128] bf16 (B^T layout), B2T[64][128] bf16 ----------
__global__ void prep_kernel(const float* __restrict__ basis,   // [30][128][64]
                            const float* __restrict__ comp,    // [8][30]
                            const float* __restrict__ root,    // [128][64]
                            const float* __restrict__ w_rel,   // [64][64]
                            const float* __restrict__ w_root,  // [64][64]
                            unsigned short* __restrict__ WcatT, // [576][128] bf16
                            unsigned short* __restrict__ B2T)   // [64][128] bf16
{
    int idx = blockIdx.x * blockDim.x + threadIdx.x;
    const int totalW = NBTOT * GD;          // 73728
    if (idx < totalW) {
        int c = idx / GD;       // output col 0..575
        int i = idx % GD;       // k 0..127
        float v;
        if (c < NREL * H1) {
            int r = c >> 6, o = c & 63;
            float acc = 0.f;
            #pragma unroll 5
            for (int b = 0; b < NBASES; ++b)
                acc += comp[r * NBASES + b] * basis[(b * GD + i) * H1 + o];
            v = acc;
        } else {
            v = root[i * H1 + (c - NREL * H1)];
        }
        WcatT[idx] = f2bf(v);
    } else {
        int j = idx - totalW;               // 0..8191
        if (j < H2 * GD) {
            int o = j / GD, i = j % GD;
            float v = (i < H1) ? w_rel[i * H2 + o] : w_root[(i - H1) * H2 + o];
            B2T[j] = f2bf(v);
        }
    }
}

// ---------- bucket histogram: bcnt[b] = #edges with dst in bucket b ----------
__global__ __launch_bounds__(512)
void bucket_count(const int* __restrict__ ei, unsigned* __restrict__ bcnt)
{
    __shared__ unsigned l[NBUCK];
    int t = threadIdx.x;
    int c0 = blockIdx.x * ECHUNK;
    int c1 = c0 + ECHUNK; if (c1 > NE) c1 = NE;
    for (int i = t; i < NBUCK; i += 512) l[i] = 0;
    __syncthreads();
    for (int e = c0 + t; e < c1; e += 512)
        atomicAdd(&l[ei[NE + e] >> 8], 1u);
    __syncthreads();
    for (int i = t; i < NBUCK; i += 512)
        if (l[i]) atomicAdd(&bcnt[i], l[i]);
}

// ---------- scan 391 bucket counts -> boff[392], bcur, off[NN] ----------
__global__ __launch_bounds__(512)
void bucket_scan(const unsigned* __restrict__ bcnt,
                 unsigned* __restrict__ boff,
                 unsigned* __restrict__ bcur,
                 unsigned* __restrict__ off)
{
    __shared__ unsigned s[512];
    int t = threadIdx.x;
    unsigned v = (t < NBUCK) ? bcnt[t] : 0u;
    s[t] = v;
    __syncthreads();
    for (int st = 1; st < 512; st <<= 1) {
        unsigned u = (t >= st) ? s[t - st] : 0u;
        __syncthreads();
        s[t] += u;
        __syncthreads();
    }
    if (t < NBUCK) { boff[t] = s[t] - v; bcur[t] = s[t] - v; }
    if (t == 511) { boff[NBUCK] = s[511]; off[NN] = s[511]; }
}

// ---------- partition phase A: bucket-grouped records, coalesced writes ----------
// tmp record: {(dstlocal<<24)|(src<<3)|r, norm_bits}
__global__ __launch_bounds__(512)
void partition_a(const int* __restrict__ ei, const int* __restrict__ et,
                 const float* __restrict__ enorm,
                 unsigned* __restrict__ bcur,
                 uint2* __restrict__ tmp)
{
    __shared__ unsigned lcnt[NBUCK], wbase[NBUCK], lcur[NBUCK];
    int t = threadIdx.x;
    int c0 = blockIdx.x * ECHUNK;
    int c1 = c0 + ECHUNK; if (c1 > NE) c1 = NE;
    for (int i = t; i < NBUCK; i += 512) { lcnt[i] = 0; lcur[i] = 0; }
    __syncthreads();
    for (int e = c0 + t; e < c1; e += 512) {
        int dst = ei[NE + e];
        atomicAdd(&lcnt[dst >> 8], 1u);
    }
    __syncthreads();
    for (int i = t; i < NBUCK; i += 512)
        wbase[i] = atomicAdd(&bcur[i], lcnt[i]);
    __syncthreads();
    for (int e = c0 + t; e < c1; e += 512) {
        int src = ei[e], dst = ei[NE + e], r = et[e];
        int b = dst >> 8;
        unsigned pos = wbase[b] + atomicAdd(&lcur[b], 1u);
        unsigned dl = (unsigned)(dst & (NPB - 1));
        tmp[pos] = make_uint2((dl << 24) | ((unsigned)src << 3) | (unsigned)r,
                              __float_as_uint(enorm[e]));
    }
}

// ---------- partition phase B: per-bucket count + scan + scatter ----------
// writes off[n], cnt[n][8] (coalesced) and final CSR records
__global__ __launch_bounds__(512)
void partition_b(const unsigned* __restrict__ boff,
                 const uint2* __restrict__ tmp,
                 uint2* __restrict__ csr,
                 unsigned* __restrict__ off,
                 unsigned* __restrict__ cnt)
{
    __shared__ unsigned lcnt[NPB * NREL];   // 8 KB
    __shared__ unsigned sscan[256];
    __shared__ unsigned lcur[NPB];
    int b = blockIdx.x, t = threadIdx.x;
    int nlo = b * NPB;
    int nn = NN - nlo; if (nn > NPB) nn = NPB;
    for (int i = t; i < NPB * NREL; i += 512) lcnt[i] = 0;
    __syncthreads();
    unsigned bstart = boff[b], bend = boff[b + 1];
    for (unsigned j = bstart + t; j < bend; j += 512) {
        unsigned x = tmp[j].x;
        atomicAdd(&lcnt[((x >> 24) << 3) | (x & 7u)], 1u);
    }
    __syncthreads();
    // per-node totals + scan (threads 0..255 participate)
    unsigned tot = 0;
    if (t < 256) {
        if (t < nn) {
            #pragma unroll
            for (int r = 0; r < NREL; ++r) tot += lcnt[t * NREL + r];
        }
        sscan[t] = tot;
    }
    __syncthreads();
    for (int st = 1; st < 256; st <<= 1) {
        unsigned u = (t < 256 && t >= st) ? sscan[t - st] : 0u;
        __syncthreads();
        if (t < 256) sscan[t] += u;
        __syncthreads();
    }
    if (t < nn) {
        unsigned ex = bstart + sscan[t] - tot;
        off[nlo + t] = ex;
        lcur[t] = ex;
        *reinterpret_cast<uint4*>(&cnt[(size_t)(nlo + t) * NREL]) =
            *reinterpret_cast<uint4*>(&lcnt[t * NREL]);
        *reinterpret_cast<uint4*>(&cnt[(size_t)(nlo + t) * NREL + 4]) =
            *reinterpret_cast<uint4*>(&lcnt[t * NREL + 4]);
    }
    __syncthreads();
    for (unsigned j = bstart + t; j < bend; j += 512) {
        uint2 rec = tmp[j];
        unsigned dl = rec.x >> 24;
        unsigned p = atomicAdd(&lcur[dl], 1u);
        csr[p] = make_uint2(rec.x & 0x00FFFFFFu, rec.y);
    }
}

// ---------- MFMA GEMM ----------
// MODE 0 (NT=9, A fp32): cols 0..511 -> y bf16 [N][512]; cols 512..575 -> root1[n*64+o]+bias
// MODE 1 (NT=1, A bf16 [M][128]): out[n*64+col] = acc + bias[col]
// XOR-swizzled LDS (T2): 16B slot index ^= (row&7) — conflict-free ds_read_b128.
template<int MODE>
__global__ __launch_bounds__(256)
void mfma_gemm(const void* __restrict__ Avoid,
               const unsigned short* __restrict__ Bt,
               int M,
               const float* __restrict__ bias,
               unsigned short* __restrict__ y,
               float* __restrict__ root1,
               float* __restrict__ out)
{
    constexpr int NT = (MODE == 0) ? 9 : 1;
    __shared__ unsigned short Alds[128 * 128];   // 32 KB, swizzled
    __shared__ unsigned short Blds[64 * 128];    // 16 KB, swizzled

    int tid = threadIdx.x;
    int m0 = blockIdx.x * 128;
    int w = tid >> 6, l = tid & 63;
    int lr = l & 15, lk = l >> 4;

    if (MODE == 0) {
        const float* A = (const float*)Avoid;
        #pragma unroll
        for (int p = 0; p < 16; ++p) {
            int f = p * 256 + tid;          // 0..4095 float4s
            int r = f >> 5;                 // row 0..127
            int c4 = f & 31;                // float4 col 0..31
            float4 av = make_float4(0.f, 0.f, 0.f, 0.f);
            if (m0 + r < M)
                av = *reinterpret_cast<const float4*>(&A[(size_t)(m0 + r) * GD + c4 * 4]);
            ushort4 bv;
            bv.x = f2bf(av.x); bv.y = f2bf(av.y); bv.z = f2bf(av.z); bv.w = f2bf(av.w);
            int slot = (c4 >> 1) ^ (r & 7);
            int byte = r * 256 + (slot << 4) + ((c4 & 1) << 3);
            *reinterpret_cast<ushort4*>(reinterpret_cast<char*>(Alds) + byte) = bv;
        }
    } else {
        const unsigned short* A = (const unsigned short*)Avoid;
        #pragma unroll
        for (int p = 0; p < 8; ++p) {
            int f = p * 256 + tid;          // 0..2047 16B-chunks
            int r = f >> 4;                 // row 0..127
            int slot = f & 15;
            uint4 v = make_uint4(0u, 0u, 0u, 0u);
            if (m0 + r < M)
                v = *reinterpret_cast<const uint4*>(&A[(size_t)(m0 + r) * GD + slot * 8]);
            int byte = r * 256 + ((slot ^ (r & 7)) << 4);
            *reinterpret_cast<uint4*>(reinterpret_cast<char*>(Alds) + byte) = v;
        }
    }

    for (int nt = 0; nt < NT; ++nt) {
        #pragma unroll
        for (int p = 0; p < 4; ++p) {
            int f = p * 256 + tid;      // 0..1023 16B-chunks
            int c = f >> 4;             // col 0..63
            int slot = f & 15;
            uint4 v = *reinterpret_cast<const uint4*>(&Bt[(size_t)(nt * 64 + c) * GD + slot * 8]);
            int byte = c * 256 + (((slot ^ (c & 7)) << 4));
            *reinterpret_cast<uint4*>(reinterpret_cast<char*>(Blds) + byte) = v;
        }
        __syncthreads();

        f32x4 acc[2][4];
        #pragma unroll
        for (int i = 0; i < 2; ++i)
            #pragma unroll
            for (int j = 0; j < 4; ++j)
                acc[i][j] = (f32x4){0.f, 0.f, 0.f, 0.f};

        #pragma unroll
        for (int ks = 0; ks < 4; ++ks) {
            int q = 4 * ks + lk;
            int sA = q ^ (lr & 7);
            bf16x8 a0 = *reinterpret_cast<const bf16x8*>(
                reinterpret_cast<char*>(Alds) + (w * 32 + 0 * 16 + lr) * 256 + (sA << 4));
            bf16x8 a1 = *reinterpret_cast<const bf16x8*>(
                reinterpret_cast<char*>(Alds) + (w * 32 + 1 * 16 + lr) * 256 + (sA << 4));
            #pragma unroll
            for (int cf = 0; cf < 4; ++cf) {
                bf16x8 b = *reinterpret_cast<const bf16x8*>(
                    reinterpret_cast<char*>(Blds) + (cf * 16 + lr) * 256 + (sA << 4));
                acc[0][cf] = __builtin_amdgcn_mfma_f32_16x16x32_bf16(a0, b, acc[0][cf], 0, 0, 0);
                acc[1][cf] = __builtin_amdgcn_mfma_f32_16x16x32_bf16(a1, b, acc[1][cf], 0, 0, 0);
            }
        }

        #pragma unroll
        for (int rf = 0; rf < 2; ++rf) {
            int rowb = m0 + w * 32 + rf * 16 + lk * 4;
            #pragma unroll
            for (int cf = 0; cf < 4; ++cf) {
                int col = nt * 64 + cf * 16 + lr;
                #pragma unroll
                for (int j = 0; j < 4; ++j) {
                    int row = rowb + j;
                    if (row >= M) continue;
                    float v = acc[rf][cf][j];
                    if (MODE == 0) {
                        if (col < NREL * H1)
                            y[(size_t)row * 512 + col] = f2bf(v);
                        else
                            root1[(size_t)row * 64 + (col - NREL * H1)] = v + bias[col - NREL * H1];
                    } else {
                        out[(size_t)row * H2 + col] = v + bias[col];
                    }
                }
            }
        }
        __syncthreads();
    }
}

// ---------- RGCN aggregate: wave per node, lane = h1 dim, 4-deep MLP ----------
__global__ void rgcn_aggregate(const unsigned* __restrict__ off,
                               const uint2* __restrict__ csr,
                               const unsigned* __restrict__ cnt,
                               const unsigned short* __restrict__ y,
                               const float* __restrict__ root1,
                               unsigned short* __restrict__ abuf)
{
    int gid = blockIdx.x * blockDim.x + threadIdx.x;
    int n = gid >> 6;
    int lane = gid & 63;
    if (n >= NN) return;
    unsigned myc = (lane < NREL) ? cnt[(size_t)n * NREL + lane] : 1u;
    float myinv = 1.0f / (float)(myc > 0u ? myc : 1u);
    unsigned s = off[n], e = off[n + 1];
    float a0 = 0.f, a1 = 0.f, a2 = 0.f, a3 = 0.f;
    unsigned i = s;
    for (; i + 4 <= e; i += 4) {
        uint2 q0 = csr[i], q1 = csr[i + 1], q2 = csr[i + 2], q3 = csr[i + 3];
        float v0 = bf2f(y[(size_t)q0.x * 64 + lane]);
        float v1 = bf2f(y[(size_t)q1.x * 64 + lane]);
        float v2 = bf2f(y[(size_t)q2.x * 64 + lane]);
        float v3 = bf2f(y[(size_t)q3.x * 64 + lane]);
        a0 += v0 * __shfl(myinv, (int)(q0.x & 7));
        a1 += v1 * __shfl(myinv, (int)(q1.x & 7));
        a2 += v2 * __shfl(myinv, (int)(q2.x & 7));
        a3 += v3 * __shfl(myinv, (int)(q3.x & 7));
    }
    for (; i < e; ++i) {
        uint2 q = csr[i];
        a0 += bf2f(y[(size_t)q.x * 64 + lane]) * __shfl(myinv, (int)(q.x & 7));
    }
    float out1 = root1[(size_t)n * 64 + lane] + ((a0 + a1) + (a2 + a3));
    abuf[(size_t)n * 128 + 64 + lane] = f2bf(out1);
}

// ---------- GraphConv aggregate: 4-deep MLP ----------
__global__ void graph_aggregate(const unsigned* __restrict__ off,
                                const uint2* __restrict__ csr,
                                unsigned short* __restrict__ abuf)
{
    int gid = blockIdx.x * blockDim.x + threadIdx.x;
    int n = gid >> 6;
    int lane = gid & 63;
    if (n >= NN) return;
    unsigned s = off[n], e = off[n + 1];
    float a0 = 0.f, a1 = 0.f, a2 = 0.f, a3 = 0.f;
    unsigned i = s;
    for (; i + 4 <= e; i += 4) {
        uint2 q0 = csr[i], q1 = csr[i + 1], q2 = csr[i + 2], q3 = csr[i + 3];
        float v0 = bf2f(abuf[(size_t)(q0.x >> 3) * 128 + 64 + lane]);
        float v1 = bf2f(abuf[(size_t)(q1.x >> 3) * 128 + 64 + lane]);
        float v2 = bf2f(abuf[(size_t)(q2.x >> 3) * 128 + 64 + lane]);
        float v3 = bf2f(abuf[(size_t)(q3.x >> 3) * 128 + 64 + lane]);
        a0 += v0 * __uint_as_float(q0.y);
        a1 += v1 * __uint_as_float(q1.y);
        a2 += v2 * __uint_as_float(q2.y);
        a3 += v3 * __uint_as_float(q3.y);
    }
    for (; i < e; ++i) {
        uint2 q = csr[i];
        a0 += bf2f(abuf[(size_t)(q.x >> 3) * 128 + 64 + lane]) * __uint_as_float(q.y);
    }
    abuf[(size_t)n * 128 + lane] = f2bf(((a0 + a1) + (a2 + a3)));
}

extern "C" void kernel_launch(void* const* d_in, const int* in_sizes, int n_in,
                              void* d_out, int out_size, void* d_ws, size_t ws_size,
                              hipStream_t stream)
{
    const float* node_features = (const float*)d_in[0];
    const int*   edge_index    = (const int*)d_in[1];
    const float* edge_norm     = (const float*)d_in[2];
    const int*   edge_type     = (const int*)d_in[3];
    const float* basis         = (const float*)d_in[4];
    const float* comp          = (const float*)d_in[5];
    const float* root          = (const float*)d_in[6];
    const float* bias1         = (const float*)d_in[7];
    const float* w_rel         = (const float*)d_in[8];
    const float* b_rel         = (const float*)d_in[9];
    const float* w_root        = (const float*)d_in[10];
    float* out = (float*)d_out;

    char* ws = (char*)d_ws;
    size_t o = 0;
    auto alloc = [&](size_t bytes) -> void* {
        o = (o + 511) & ~(size_t)511;
        void* p = ws + o;
        o += bytes;
        return p;
    };
    unsigned short* WcatT = (unsigned short*)alloc((size_t)NBTOT * GD * 2);
    unsigned short* B2T   = (unsigned short*)alloc((size_t)H2 * GD * 2);
    unsigned* cnt      = (unsigned*)alloc((size_t)NN * NREL * 4);
    unsigned* off_     = (unsigned*)alloc((size_t)(NN + 1) * 4);
    unsigned* bcnt     = (unsigned*)alloc((size_t)NBUCK * 4);
    unsigned* boff     = (unsigned*)alloc((size_t)(NBUCK + 1) * 4);
    unsigned* bcur     = (unsigned*)alloc((size_t)NBUCK * 4);
    uint2*    csr      = (uint2*)alloc((size_t)NE * 8);
    unsigned short* y  = (unsigned short*)alloc((size_t)NN * 512 * 2);
    float*    root1    = (float*)alloc((size_t)NN * 64 * 4);
    unsigned short* abuf = (unsigned short*)alloc((size_t)NN * 128 * 2);
    uint2*    tmp      = (uint2*)abuf;   // alias: tmp dead before abuf's first write
    // (abuf is 25.6 MB >= tmp's 12.8 MB; tmp used partition_a->partition_b only)

    hipMemsetAsync(bcnt, 0, (size_t)NBUCK * 4, stream);

    prep_kernel<<<(NBTOT * GD + H2 * GD + 255) / 256, 256, 0, stream>>>(
        basis, comp, root, w_rel, w_root, WcatT, B2T);

    bucket_count<<<NWGA, 512, 0, stream>>>(edge_index, bcnt);
    bucket_scan<<<1, 512, 0, stream>>>(bcnt, boff, bcur, off_);
    partition_a<<<NWGA, 512, 0, stream>>>(edge_index, edge_type, edge_norm, bcur, tmp);
    partition_b<<<NBUCK, 512, 0, stream>>>(boff, tmp, csr, off_, cnt);

    int gblk = (NN + 127) / 128;   // 782
    mfma_gemm<0><<<gblk, 256, 0, stream>>>(node_features, WcatT, NN, bias1, y, root1, nullptr);

    rgcn_aggregate<<<(NN * 64 + 255) / 256, 256, 0, stream>>>(off_, csr, cnt, y, root1, abuf);

    graph_aggregate<<<(NN * 64 + 255) / 256, 256, 0, stream>>>(off_, csr, abuf);

    mfma_gemm<1><<<gblk, 256, 0, stream>>>(abuf, B2T, NN, b_rel, nullptr, nullptr, out);
}